// Round 2
// baseline (872.643 us; speedup 1.0000x reference)
//
#include <hip/hip_runtime.h>
#include <cstdint>

typedef unsigned short u16;
typedef __attribute__((ext_vector_type(8))) short sh8;   // 8 bf16 (4 VGPRs)
typedef __attribute__((ext_vector_type(4))) float f32x4;

struct __align__(8) us4 { u16 x, y, z, w; };

__device__ __forceinline__ u16 f2bf(float f) {
  unsigned u = __float_as_uint(f);
  u += 0x7FFFu + ((u >> 16) & 1u);   // RNE
  return (u16)(u >> 16);
}
__device__ __forceinline__ float bf2f(u16 h) {
  return __uint_as_float((unsigned)h << 16);
}

// ---------------- block reductions (blockDim.x == 256) ----------------
__device__ __forceinline__ float blk_sum(float v, float* red) {
#pragma unroll
  for (int o = 32; o; o >>= 1) v += __shfl_xor(v, o);
  __syncthreads();
  if ((threadIdx.x & 63) == 0) red[threadIdx.x >> 6] = v;
  __syncthreads();
  return red[0] + red[1] + red[2] + red[3];
}
__device__ __forceinline__ float blk_max(float v, float* red) {
#pragma unroll
  for (int o = 32; o; o >>= 1) v = fmaxf(v, __shfl_xor(v, o));
  __syncthreads();
  if ((threadIdx.x & 63) == 0) red[threadIdx.x >> 6] = v;
  __syncthreads();
  return fmaxf(fmaxf(red[0], red[1]), fmaxf(red[2], red[3]));
}

// ---------------- fp32 -> bf16 ----------------
__global__ void cvt_bf16(const float* __restrict__ S, u16* __restrict__ D, long n4) {
  long i = (long)blockIdx.x * blockDim.x + threadIdx.x;
  if (i >= n4) return;
  float4 v = ((const float4*)S)[i];
  us4 o; o.x = f2bf(v.x); o.y = f2bf(v.y); o.z = f2bf(v.z); o.w = f2bf(v.w);
  ((us4*)D)[i] = o;
}

__global__ void fillv(float* __restrict__ o, long n, float v) {
  long i = (long)blockIdx.x * blockDim.x + threadIdx.x;
  if (i < n) o[i] = v;
}

// ---------------- bf16 GEMM: C[M,N] = A[M,K] @ B[N,K]^T (strided A/B rows) ----
// m97 structure: 128x128 tile, BK=32, 4 waves (64x64 each), global_load_lds w16.
template <typename CT>
__global__ __launch_bounds__(256, 2) void gemm_bt(
    const u16* __restrict__ A, const u16* __restrict__ B, CT* __restrict__ C,
    int M, int N, int K, int lda, int ldb, int causal) {
  int bm = blockIdx.x, bn = blockIdx.y;
  if (causal && bn > bm) return;
  __shared__ __align__(16) u16 As[128 * 32];
  __shared__ __align__(16) u16 Bs[128 * 32];
  int tid = threadIdx.x, wid = tid >> 6, lane = tid & 63;
  int wr = (wid >> 1) << 6, wc = (wid & 1) << 6;
  int lr = lane & 15, lk = (lane >> 4) << 3;

  f32x4 acc[4][4];
  const f32x4 z = {0.f, 0.f, 0.f, 0.f};
#pragma unroll
  for (int i = 0; i < 4; ++i)
#pragma unroll
    for (int j = 0; j < 4; ++j) acc[i][j] = z;

  int r0 = tid >> 2, c0 = (tid & 3) << 3;   // staging: row tid/4, col (tid%4)*8
  const size_t baseA = (size_t)bm * 128, baseB = (size_t)bn * 128;
  const u16* Ab = A + baseA * lda;
  const u16* Bp = B + baseB * ldb;

  for (int k0 = 0; k0 < K; k0 += 32) {
    __builtin_amdgcn_global_load_lds(
        (const __attribute__((address_space(1))) void*)(Ab + (size_t)r0 * lda + k0 + c0),
        (__attribute__((address_space(3))) void*)(As + (wid << 9)), 16, 0, 0);
    __builtin_amdgcn_global_load_lds(
        (const __attribute__((address_space(1))) void*)(Ab + (size_t)(64 + r0) * lda + k0 + c0),
        (__attribute__((address_space(3))) void*)(As + 2048 + (wid << 9)), 16, 0, 0);
    __builtin_amdgcn_global_load_lds(
        (const __attribute__((address_space(1))) void*)(Bp + (size_t)r0 * ldb + k0 + c0),
        (__attribute__((address_space(3))) void*)(Bs + (wid << 9)), 16, 0, 0);
    __builtin_amdgcn_global_load_lds(
        (const __attribute__((address_space(1))) void*)(Bp + (size_t)(64 + r0) * ldb + k0 + c0),
        (__attribute__((address_space(3))) void*)(Bs + 2048 + (wid << 9)), 16, 0, 0);
    __syncthreads();
    sh8 af[4], bfr[4];
#pragma unroll
    for (int f = 0; f < 4; ++f) {
      af[f]  = *(const sh8*)(As + (wr + f * 16 + lr) * 32 + lk);
      bfr[f] = *(const sh8*)(Bs + (wc + f * 16 + lr) * 32 + lk);
    }
#pragma unroll
    for (int i = 0; i < 4; ++i)
#pragma unroll
      for (int j = 0; j < 4; ++j)
        acc[i][j] = __builtin_amdgcn_mfma_f32_16x16x32_bf16(af[i], bfr[j], acc[i][j], 0, 0, 0);
    __syncthreads();
  }

  // C/D layout (m89): col = lane&15, row = (lane>>4)*4 + reg
  int cr = (lane >> 4) << 2, cc = lane & 15;
#pragma unroll
  for (int i = 0; i < 4; ++i)
#pragma unroll
    for (int j = 0; j < 4; ++j) {
      size_t cb = (baseA + wr + i * 16 + cr) * (size_t)N + (baseB + wc + j * 16 + cc);
#pragma unroll
      for (int r = 0; r < 4; ++r) {
        float v = acc[i][j][r];
        if constexpr (sizeof(CT) == 2) C[cb + (size_t)r * N] = (CT)f2bf(v);
        else                           C[cb + (size_t)r * N] = v;
      }
    }
}

// ---------------- row LayerNorm (fp32 in) -> bf16 out + row L2 norm ----------------
__global__ void ln_rows(const float* __restrict__ X, const float* __restrict__ w,
                        const float* __restrict__ b, u16* __restrict__ Y,
                        float* __restrict__ norms, int C) {
  __shared__ float red[4];
  int row = blockIdx.x;
  const float* x = X + (size_t)row * C;
  int nv = C >> 2;
  float s = 0.f, ss = 0.f;
  for (int i = threadIdx.x; i < nv; i += 256) {
    float4 v = ((const float4*)x)[i];
    s += v.x + v.y + v.z + v.w;
    ss += v.x * v.x + v.y * v.y + v.z * v.z + v.w * v.w;
  }
  s = blk_sum(s, red);
  ss = blk_sum(ss, red);
  float mean = s / C;
  float inv = rsqrtf(fmaxf(ss / C - mean * mean, 0.f) + 1e-5f);
  float nrm = 0.f;
  for (int i = threadIdx.x; i < nv; i += 256) {
    float4 v = ((const float4*)x)[i];
    float4 wv = ((const float4*)w)[i];
    float4 bv = ((const float4*)b)[i];
    float y0 = (v.x - mean) * inv * wv.x + bv.x;
    float y1 = (v.y - mean) * inv * wv.y + bv.y;
    float y2 = (v.z - mean) * inv * wv.z + bv.z;
    float y3 = (v.w - mean) * inv * wv.w + bv.w;
    nrm += y0 * y0 + y1 * y1 + y2 * y2 + y3 * y3;
    us4 o; o.x = f2bf(y0); o.y = f2bf(y1); o.z = f2bf(y2); o.w = f2bf(y3);
    ((us4*)(Y + (size_t)row * C))[i] = o;
  }
  nrm = blk_sum(nrm, red);
  if (threadIdx.x == 0) norms[row] = fmaxf(sqrtf(nrm), 1e-12f);
}

// ---------------- eff proto: E = proto + LN(T) -> bf16 + row norm ----------------
__global__ void ln_add_norm(const float* __restrict__ T, const float* __restrict__ P,
                            const float* __restrict__ w, const float* __restrict__ b,
                            u16* __restrict__ E, float* __restrict__ norms, int C) {
  __shared__ float red[4];
  int row = blockIdx.x;
  const float* t = T + (size_t)row * C;
  const float* p = P + (size_t)row * C;
  int nv = C >> 2;
  float s = 0.f, ss = 0.f;
  for (int i = threadIdx.x; i < nv; i += 256) {
    float4 v = ((const float4*)t)[i];
    s += v.x + v.y + v.z + v.w;
    ss += v.x * v.x + v.y * v.y + v.z * v.z + v.w * v.w;
  }
  s = blk_sum(s, red);
  ss = blk_sum(ss, red);
  float mean = s / C;
  float inv = rsqrtf(fmaxf(ss / C - mean * mean, 0.f) + 1e-5f);
  float nrm = 0.f;
  for (int i = threadIdx.x; i < nv; i += 256) {
    float4 v = ((const float4*)t)[i];
    float4 pv = ((const float4*)p)[i];
    float4 wv = ((const float4*)w)[i];
    float4 bv = ((const float4*)b)[i];
    float y0 = pv.x + (v.x - mean) * inv * wv.x + bv.x;
    float y1 = pv.y + (v.y - mean) * inv * wv.y + bv.y;
    float y2 = pv.z + (v.z - mean) * inv * wv.z + bv.z;
    float y3 = pv.w + (v.w - mean) * inv * wv.w + bv.w;
    nrm += y0 * y0 + y1 * y1 + y2 * y2 + y3 * y3;
    us4 o; o.x = f2bf(y0); o.y = f2bf(y1); o.z = f2bf(y2); o.w = f2bf(y3);
    ((us4*)(E + (size_t)row * C))[i] = o;
  }
  nrm = blk_sum(nrm, red);
  if (threadIdx.x == 0) norms[row] = fmaxf(sqrtf(nrm), 1e-12f);
}

// ---------------- row L2 norm of a bf16 matrix ----------------
__global__ void rownorm_bf(const u16* __restrict__ X, float* __restrict__ norms, int C) {
  __shared__ float red[4];
  int row = blockIdx.x;
  const us4* x = (const us4*)(X + (size_t)row * C);
  int nv = C >> 2;
  float nrm = 0.f;
  for (int i = threadIdx.x; i < nv; i += 256) {
    us4 v = x[i];
    float a = bf2f(v.x), b = bf2f(v.y), c = bf2f(v.z), d = bf2f(v.w);
    nrm += a * a + b * b + c * c + d * d;
  }
  nrm = blk_sum(nrm, red);
  if (threadIdx.x == 0) norms[row] = fmaxf(sqrtf(nrm), 1e-12f);
}

// ---------------- SPL epilogue (bf16 comp/dots in, bf16 or fp32 out) ----------------
template <typename OT>
__global__ void spl_epi(const u16* __restrict__ comp, const u16* __restrict__ dots,
                        const float* __restrict__ bias, const float* __restrict__ gate,
                        const float* __restrict__ rn, const float* __restrict__ cn,
                        const float* __restrict__ resid, OT* __restrict__ out,
                        int C, long total, int relu_out) {
  long i = (long)blockIdx.x * blockDim.x + threadIdx.x;
  if (i >= total) return;
  long r = i / C;
  int c = (int)(i - r * C);
  float sc = bf2f(dots[i]) / (rn[r] * cn[c]);
  float v = (bf2f(comp[i]) + bias[c]) * fmaxf(sc - gate[c], 0.f);
  if (relu_out) v = fmaxf(v, 0.f);
  if (resid) v += resid[i];
  if constexpr (sizeof(OT) == 2) out[i] = (OT)f2bf(v);
  else                           out[i] = v;
}

// ---------------- RoPE in-place on bf16 m_qkv rows [*, 3072] ----------------
__global__ void rope_ip(u16* __restrict__ MQ, const float* __restrict__ CT_,
                        const float* __restrict__ ST_) {
  long t = (long)blockIdx.x * blockDim.x + threadIdx.x;  // R*512 threads
  int i = (int)(t & 511);
  long row = t >> 9;
  int s = (int)(row & 2047);
  u16* base = MQ + row * 3072;
  float c0 = CT_[(size_t)s * 1024 + i], c1 = CT_[(size_t)s * 1024 + 512 + i];
  float s0 = ST_[(size_t)s * 1024 + i], s1 = ST_[(size_t)s * 1024 + 512 + i];
  float q0 = bf2f(base[i]), q1 = bf2f(base[512 + i]);
  base[i]        = f2bf(q0 * c0 - q1 * s0);
  base[512 + i]  = f2bf(q1 * c1 + q0 * s1);
  float k0 = bf2f(base[1024 + i]), k1 = bf2f(base[1536 + i]);
  base[1024 + i] = f2bf(k0 * c0 - k1 * s0);
  base[1536 + i] = f2bf(k1 * c1 + k0 * s1);
}

// ---------------- V transpose (bf16 m_qkv -> VT[b][d][s]) ----------------
__global__ void vtrans(const u16* __restrict__ MQ, u16* __restrict__ VT) {
  __shared__ u16 tile[32][33];
  int b = blockIdx.z;
  int s0 = blockIdx.x << 5, d0 = blockIdx.y << 5;
  int tx = threadIdx.x, ty = threadIdx.y;
  for (int r = ty; r < 32; r += 8)
    tile[r][tx] = MQ[((size_t)(b * 2048 + s0 + r)) * 3072 + 2048 + d0 + tx];
  __syncthreads();
  for (int r = ty; r < 32; r += 8)
    VT[(size_t)b * 1024 * 2048 + (size_t)(d0 + r) * 2048 + s0 + tx] = tile[tx][r];
}

// ---------------- causal softmax rows of [2048,2048], scale 1/32 -> bf16 ----------------
__global__ void softmax_causal(const float* __restrict__ S, u16* __restrict__ P) {
  __shared__ float red[4];
  int q = blockIdx.x;
  const float* row = S + (size_t)q * 2048;
  u16* prow = P + (size_t)q * 2048;
  int nv = q + 1;
  int base = threadIdx.x * 8;
  float xv[8];
  float4 a = *(const float4*)(row + base);
  float4 bq = *(const float4*)(row + base + 4);
  xv[0] = a.x; xv[1] = a.y; xv[2] = a.z; xv[3] = a.w;
  xv[4] = bq.x; xv[5] = bq.y; xv[6] = bq.z; xv[7] = bq.w;
  float m = -3.4e38f;
#pragma unroll
  for (int j = 0; j < 8; ++j) {
    xv[j] *= 0.03125f;
    if (base + j < nv) m = fmaxf(m, xv[j]);
  }
  m = blk_max(m, red);
  float e[8];
  float ssum = 0.f;
#pragma unroll
  for (int j = 0; j < 8; ++j) {
    e[j] = (base + j < nv) ? __expf(xv[j] - m) : 0.f;
    ssum += e[j];
  }
  ssum = blk_sum(ssum, red);
  float invs = 1.f / ssum;
  us4 o;
  o.x = f2bf(e[0] * invs); o.y = f2bf(e[1] * invs);
  o.z = f2bf(e[2] * invs); o.w = f2bf(e[3] * invs);
  ((us4*)prow)[threadIdx.x * 2] = o;
  o.x = f2bf(e[4] * invs); o.y = f2bf(e[5] * invs);
  o.z = f2bf(e[6] * invs); o.w = f2bf(e[7] * invs);
  ((us4*)prow)[threadIdx.x * 2 + 1] = o;
}

// =============================== launcher ===============================
extern "C" void kernel_launch(void* const* d_in, const int* in_sizes, int n_in,
                              void* d_out, int out_size, void* d_ws, size_t ws_size,
                              hipStream_t stream) {
  (void)in_sizes; (void)out_size;
  const float* x         = (const float*)d_in[0];
  const float* cosT      = (const float*)d_in[1];
  const float* sinT      = (const float*)d_in[2];
  const float* ln1_w     = (const float*)d_in[3];
  const float* ln1_b     = (const float*)d_in[4];
  const float* ln2_w     = (const float*)d_in[5];
  const float* ln2_b     = (const float*)d_in[6];
  const float* qkv_mu    = (const float*)d_in[7];
  const float* qkv_proto = (const float*)d_in[8];
  const float* qkv_bias  = (const float*)d_in[9];
  const float* qkv_gate  = (const float*)d_in[10];
  const float* o_mu      = (const float*)d_in[11];
  const float* o_proto   = (const float*)d_in[12];
  const float* o_bias    = (const float*)d_in[13];
  const float* o_gate    = (const float*)d_in[14];
  const float* f1_mu     = (const float*)d_in[15];
  const float* f1_proto  = (const float*)d_in[16];
  const float* f1_bias   = (const float*)d_in[17];
  const float* f1_gate   = (const float*)d_in[18];
  const float* f2_mu     = (const float*)d_in[19];
  const float* f2_proto  = (const float*)d_in[20];
  const float* f2_bias   = (const float*)d_in[21];
  const float* f2_gate   = (const float*)d_in[22];
  const float* pt_qkv    = (const float*)d_in[23];
  const float* pt_o      = (const float*)d_in[24];
  const float* pt_f1     = (const float*)d_in[25];
  const float* pt_f2     = (const float*)d_in[26];
  const float* pln_qkv_w = (const float*)d_in[27];
  const float* pln_qkv_b = (const float*)d_in[28];
  const float* pln_o_w   = (const float*)d_in[29];
  const float* pln_o_b   = (const float*)d_in[30];
  const float* pln_f1_w  = (const float*)d_in[31];
  const float* pln_f1_b  = (const float*)d_in[32];
  const float* pln_f2_w  = (const float*)d_in[33];
  const float* pln_f2_b  = (const float*)d_in[34];
  const float* prev_qkv  = (const float*)d_in[35];
  const float* prev_o    = (const float*)d_in[36];
  const float* prev_f1   = (const float*)d_in[37];
  const float* prev_f2   = (const float*)d_in[38];

  const long D = 1024, TD = 3072, FD = 4096, R = 4096;  // R = B*S

  char* W = (char*)d_ws;
  size_t off = 0;
  auto alloc = [&](size_t bytes) {
    void* p = W + off;
    off = (off + bytes + 255) & ~(size_t)255;
    return p;
  };
  // bf16 scratch regions, time-multiplexed:
  u16* RA = (u16*)alloc(33554432);   // comp region / phase-1 prev staging
  u16* RB = (u16*)alloc(33554432);   // dots region / phase-1 pt staging
  u16* RC = (u16*)alloc(33554432);   // m_qkv (phase 2-3) / h (phase 5)
  // persistent bf16 weights:
  u16* muq   = (u16*)alloc(TD * D * 2);
  u16* muo   = (u16*)alloc(D * D * 2);
  u16* muf1  = (u16*)alloc(FD * D * 2);
  u16* muf2  = (u16*)alloc(D * FD * 2);
  u16* effq  = (u16*)alloc(TD * D * 2);
  u16* effo  = (u16*)alloc(D * D * 2);
  u16* efff1 = (u16*)alloc(FD * D * 2);
  u16* efff2 = (u16*)alloc(D * FD * 2);
  float* X1 = (float*)alloc(R * D * 4);           // x + m_o (fp32)
  float* SC = (float*)alloc(2048L * 2048 * 4);    // proto TMP / scores / f2 dots
  u16* P1  = (u16*)alloc(R * D * 2);              // attn_in bf16, later ffn_in bf16
  u16* VT  = (u16*)alloc(2 * D * 2048 * 2);       // V^T per batch
  u16* PB  = (u16*)alloc(2048L * 2048 * 2);       // softmax P bf16
  u16* AOB = (u16*)alloc(R * D * 2);              // attn out bf16
  float* pnq     = (float*)alloc(TD * 4);
  float* pno     = (float*)alloc(D * 4);
  float* pnf1    = (float*)alloc(FD * 4);
  float* pnf2    = (float*)alloc(D * 4);
  float* rn_ain  = (float*)alloc(R * 4);
  float* rn_aout = (float*)alloc(R * 4);
  float* rn_ffn  = (float*)alloc(R * 4);
  float* rn_h    = (float*)alloc(R * 4);
  size_t need = off;

  if (n_in < 39 || need > ws_size) {
    // diagnostic sentinel: tells us definitively the workspace/interface was
    // the failure (absmax will be ~12345) instead of a GPU memory fault.
    long n = out_size;
    fillv<<<dim3((unsigned)((n + 255) / 256)), 256, 0, stream>>>((float*)d_out, n, 12345.0f);
    return;
  }

  auto cvt = [&](const float* s, u16* d, long n) {
    long n4 = n >> 2;
    cvt_bf16<<<dim3((unsigned)((n4 + 255) / 256)), 256, 0, stream>>>(s, d, n4);
  };
  auto gemm_bf = [&](const u16* A, const u16* Bm, u16* C, int M, int N, int K,
                     int lda, int ldb) {
    gemm_bt<u16><<<dim3((unsigned)(M / 128), (unsigned)(N / 128)), 256, 0, stream>>>(
        A, Bm, C, M, N, K, lda, ldb, 0);
  };
  auto gemm_f = [&](const u16* A, const u16* Bm, float* C, int M, int N, int K,
                    int lda, int ldb, int causal) {
    gemm_bt<float><<<dim3((unsigned)(M / 128), (unsigned)(N / 128)), 256, 0, stream>>>(
        A, Bm, C, M, N, K, lda, ldb, causal);
  };

  // ---- phase 1: effective protos (one at a time; stage prev->RA, pt->RB, T->SC) ----
  struct Proto { const float* prev; const float* pt; const float* proto;
                 const float* w; const float* b; u16* eff; float* pn; int M; int N; int K; };
  Proto protos[4] = {
    {prev_qkv, pt_qkv, qkv_proto, pln_qkv_w, pln_qkv_b, effq,  pnq,  3072, 1024, 1024},
    {prev_o,   pt_o,   o_proto,   pln_o_w,   pln_o_b,   effo,  pno,  1024, 1024, 1024},
    {prev_f1,  pt_f1,  f1_proto,  pln_f1_w,  pln_f1_b,  efff1, pnf1, 4096, 1024, 1024},
    {prev_f2,  pt_f2,  f2_proto,  pln_f2_w,  pln_f2_b,  efff2, pnf2, 1024, 4096, 4096},
  };
  for (int p = 0; p < 4; ++p) {
    Proto& pr = protos[p];
    cvt(pr.prev, RA, (long)pr.M * pr.K);
    cvt(pr.pt,   RB, (long)pr.N * pr.K);
    gemm_f(RA, RB, SC, pr.M, pr.N, pr.K, pr.K, pr.K, 0);
    ln_add_norm<<<pr.M, 256, 0, stream>>>(SC, pr.proto, pr.w, pr.b, pr.eff, pr.pn, pr.N);
  }
  cvt(qkv_mu, muq, TD * D);  cvt(o_mu, muo, D * D);
  cvt(f1_mu, muf1, FD * D);  cvt(f2_mu, muf2, D * FD);

  // ---- phase 2: attention input LN + qkv SPL ----
  ln_rows<<<4096, 256, 0, stream>>>(x, ln1_w, ln1_b, P1, rn_ain, 1024);
  gemm_bf(P1, muq,  RA, 4096, 3072, 1024, 1024, 1024);
  gemm_bf(P1, effq, RB, 4096, 3072, 1024, 1024, 1024);
  spl_epi<u16><<<dim3((unsigned)((R * TD) / 256)), 256, 0, stream>>>(
      RA, RB, qkv_bias, qkv_gate, rn_ain, pnq, nullptr, RC, 3072, R * TD, 0);

  // ---- phase 3: RoPE (in place on RC) + attention ----
  rope_ip<<<dim3((unsigned)((R * 512) / 256)), 256, 0, stream>>>(RC, cosT, sinT);
  vtrans<<<dim3(64, 32, 2), dim3(32, 8), 0, stream>>>(RC, VT);
  for (int b = 0; b < 2; ++b) {
    const u16* mq = RC + (size_t)b * 2048 * 3072;
    gemm_bt<float><<<dim3(16, 16), 256, 0, stream>>>(
        mq, mq + 1024, SC, 2048, 2048, 1024, 3072, 3072, 1);  // Q @ K^T (causal)
    softmax_causal<<<2048, 256, 0, stream>>>(SC, PB);
    gemm_bf(PB, VT + (size_t)b * 1024 * 2048, AOB + (size_t)b * 2048 * 1024,
            2048, 1024, 2048, 2048, 2048);                    // P @ V
  }
  rownorm_bf<<<4096, 256, 0, stream>>>(AOB, rn_aout, 1024);

  // ---- phase 4: o SPL + residual -> X1 (fp32) ----
  gemm_bf(AOB, muo,  RA, 4096, 1024, 1024, 1024, 1024);
  gemm_bf(AOB, effo, RB, 4096, 1024, 1024, 1024, 1024);
  spl_epi<float><<<dim3((unsigned)((R * D) / 256)), 256, 0, stream>>>(
      RA, RB, o_bias, o_gate, rn_aout, pno, x, X1, 1024, R * D, 0);

  // ---- phase 5: FFN ----
  ln_rows<<<4096, 256, 0, stream>>>(X1, ln2_w, ln2_b, P1, rn_ffn, 1024);
  gemm_bf(P1, muf1,  RA, 4096, 4096, 1024, 1024, 1024);
  gemm_bf(P1, efff1, RB, 4096, 4096, 1024, 1024, 1024);
  spl_epi<u16><<<dim3((unsigned)((R * FD) / 256)), 256, 0, stream>>>(
      RA, RB, f1_bias, f1_gate, rn_ffn, pnf1, nullptr, RC, 4096, R * FD, 1);  // h -> RC
  rownorm_bf<<<4096, 256, 0, stream>>>(RC, rn_h, 4096);
  gemm_bf(RC, muf2,  RA, 4096, 1024, 4096, 4096, 4096);   // comp2
  gemm_bf(RC, efff2, RB, 4096, 1024, 4096, 4096, 4096);   // dots2
  spl_epi<float><<<dim3((unsigned)((R * D) / 256)), 256, 0, stream>>>(
      RA, RB, f2_bias, f2_gate, rn_h, pnf2, X1, (float*)d_out, 1024, R * D, 0);
}

// Round 3
// 663.123 us; speedup vs baseline: 1.3160x; 1.3160x over previous
//
#include <hip/hip_runtime.h>
#include <cstdint>

typedef unsigned short u16;
typedef __attribute__((ext_vector_type(8))) short sh8;   // 8 bf16 (4 VGPRs)
typedef __attribute__((ext_vector_type(4))) float f32x4;

struct __align__(8) us4 { u16 x, y, z, w; };

__device__ __forceinline__ u16 f2bf(float f) {
  unsigned u = __float_as_uint(f);
  u += 0x7FFFu + ((u >> 16) & 1u);   // RNE
  return (u16)(u >> 16);
}
__device__ __forceinline__ float bf2f(u16 h) {
  return __uint_as_float((unsigned)h << 16);
}

// ---------------- block reductions (blockDim.x == 256) ----------------
__device__ __forceinline__ float blk_sum(float v, float* red) {
#pragma unroll
  for (int o = 32; o; o >>= 1) v += __shfl_xor(v, o);
  __syncthreads();
  if ((threadIdx.x & 63) == 0) red[threadIdx.x >> 6] = v;
  __syncthreads();
  return red[0] + red[1] + red[2] + red[3];
}
__device__ __forceinline__ float blk_max(float v, float* red) {
#pragma unroll
  for (int o = 32; o; o >>= 1) v = fmaxf(v, __shfl_xor(v, o));
  __syncthreads();
  if ((threadIdx.x & 63) == 0) red[threadIdx.x >> 6] = v;
  __syncthreads();
  return fmaxf(fmaxf(red[0], red[1]), fmaxf(red[2], red[3]));
}

// ---------------- fp32 -> bf16 ----------------
__global__ void cvt_bf16(const float* __restrict__ S, u16* __restrict__ D, long n4) {
  long i = (long)blockIdx.x * blockDim.x + threadIdx.x;
  if (i >= n4) return;
  float4 v = ((const float4*)S)[i];
  us4 o; o.x = f2bf(v.x); o.y = f2bf(v.y); o.z = f2bf(v.z); o.w = f2bf(v.w);
  ((us4*)D)[i] = o;
}

__global__ void fillv(float* __restrict__ o, long n, float v) {
  long i = (long)blockIdx.x * blockDim.x + threadIdx.x;
  if (i < n) o[i] = v;
}

// ---------------- bf16 GEMM: C[M,N] = A[M,K] @ B[N,K]^T ----------------
// m97 structure: 128x128 tile, BK=32, 4 waves (64x64 each), global_load_lds w16.
// mode 0: plain 2D grid.
// mode 1: split-K over blockIdx.z (gridDim.z chunks); C has per-chunk partials
//         of M*N fp32 at stride M*N.
// mode 2: batched over blockIdx.z with element strides zsA/zsB/zsC.
// mode 3: batched (as 2) + causal lower-triangle tile enumeration on blockIdx.x.
template <typename CT>
__global__ __launch_bounds__(256, 2) void gemm_bt(
    const u16* __restrict__ A, const u16* __restrict__ B, CT* __restrict__ C,
    int M, int N, int K, int lda, int ldb,
    int mode, long zsA, long zsB, long zsC) {
  int bm, bn;
  int z = blockIdx.z;
  if (mode == 3) {
    int t = blockIdx.x;
    int m = (int)floorf((sqrtf(8.f * t + 1.f) - 1.f) * 0.5f);
    while ((m + 1) * (m + 2) / 2 <= t) ++m;
    while (m * (m + 1) / 2 > t) --m;
    bm = m; bn = t - m * (m + 1) / 2;
  } else {
    bm = blockIdx.x; bn = blockIdx.y;
  }
  int k0s = 0, k0e = K;
  if (mode == 1) {
    int kc = K / gridDim.z;
    k0s = z * kc; k0e = k0s + kc;
    C += (size_t)z * M * (size_t)N;
  } else if (mode >= 2) {
    A += (size_t)z * zsA; B += (size_t)z * zsB; C += (size_t)z * zsC;
  }

  __shared__ __align__(16) u16 As[128 * 32];
  __shared__ __align__(16) u16 Bs[128 * 32];
  int tid = threadIdx.x, wid = tid >> 6, lane = tid & 63;
  int wr = (wid >> 1) << 6, wc = (wid & 1) << 6;
  int lr = lane & 15, lk = (lane >> 4) << 3;

  f32x4 acc[4][4];
  const f32x4 zf = {0.f, 0.f, 0.f, 0.f};
#pragma unroll
  for (int i = 0; i < 4; ++i)
#pragma unroll
    for (int j = 0; j < 4; ++j) acc[i][j] = zf;

  int r0 = tid >> 2, c0 = (tid & 3) << 3;
  const size_t baseA = (size_t)bm * 128, baseB = (size_t)bn * 128;
  const u16* Ab = A + baseA * lda;
  const u16* Bp = B + baseB * ldb;

  for (int k0 = k0s; k0 < k0e; k0 += 32) {
    __builtin_amdgcn_global_load_lds(
        (const __attribute__((address_space(1))) void*)(Ab + (size_t)r0 * lda + k0 + c0),
        (__attribute__((address_space(3))) void*)(As + (wid << 9)), 16, 0, 0);
    __builtin_amdgcn_global_load_lds(
        (const __attribute__((address_space(1))) void*)(Ab + (size_t)(64 + r0) * lda + k0 + c0),
        (__attribute__((address_space(3))) void*)(As + 2048 + (wid << 9)), 16, 0, 0);
    __builtin_amdgcn_global_load_lds(
        (const __attribute__((address_space(1))) void*)(Bp + (size_t)r0 * ldb + k0 + c0),
        (__attribute__((address_space(3))) void*)(Bs + (wid << 9)), 16, 0, 0);
    __builtin_amdgcn_global_load_lds(
        (const __attribute__((address_space(1))) void*)(Bp + (size_t)(64 + r0) * ldb + k0 + c0),
        (__attribute__((address_space(3))) void*)(Bs + 2048 + (wid << 9)), 16, 0, 0);
    __syncthreads();
    sh8 af[4], bfr[4];
#pragma unroll
    for (int f = 0; f < 4; ++f) {
      af[f]  = *(const sh8*)(As + (wr + f * 16 + lr) * 32 + lk);
      bfr[f] = *(const sh8*)(Bs + (wc + f * 16 + lr) * 32 + lk);
    }
#pragma unroll
    for (int i = 0; i < 4; ++i)
#pragma unroll
      for (int j = 0; j < 4; ++j)
        acc[i][j] = __builtin_amdgcn_mfma_f32_16x16x32_bf16(af[i], bfr[j], acc[i][j], 0, 0, 0);
    __syncthreads();
  }

  // C/D layout (m89): col = lane&15, row = (lane>>4)*4 + reg
  int cr = (lane >> 4) << 2, cc = lane & 15;
#pragma unroll
  for (int i = 0; i < 4; ++i)
#pragma unroll
    for (int j = 0; j < 4; ++j) {
      size_t cb = (baseA + wr + i * 16 + cr) * (size_t)N + (baseB + wc + j * 16 + cc);
#pragma unroll
      for (int r = 0; r < 4; ++r) {
        float v = acc[i][j][r];
        if constexpr (sizeof(CT) == 2) C[cb + (size_t)r * N] = (CT)f2bf(v);
        else                           C[cb + (size_t)r * N] = v;
      }
    }
}

// ---------------- row LayerNorm (fp32 in) -> bf16 out + row L2 norm ----------------
__global__ void ln_rows(const float* __restrict__ X, const float* __restrict__ w,
                        const float* __restrict__ b, u16* __restrict__ Y,
                        float* __restrict__ norms, int C) {
  __shared__ float red[4];
  int row = blockIdx.x;
  const float* x = X + (size_t)row * C;
  int nv = C >> 2;
  float s = 0.f, ss = 0.f;
  for (int i = threadIdx.x; i < nv; i += 256) {
    float4 v = ((const float4*)x)[i];
    s += v.x + v.y + v.z + v.w;
    ss += v.x * v.x + v.y * v.y + v.z * v.z + v.w * v.w;
  }
  s = blk_sum(s, red);
  ss = blk_sum(ss, red);
  float mean = s / C;
  float inv = rsqrtf(fmaxf(ss / C - mean * mean, 0.f) + 1e-5f);
  float nrm = 0.f;
  for (int i = threadIdx.x; i < nv; i += 256) {
    float4 v = ((const float4*)x)[i];
    float4 wv = ((const float4*)w)[i];
    float4 bv = ((const float4*)b)[i];
    float y0 = (v.x - mean) * inv * wv.x + bv.x;
    float y1 = (v.y - mean) * inv * wv.y + bv.y;
    float y2 = (v.z - mean) * inv * wv.z + bv.z;
    float y3 = (v.w - mean) * inv * wv.w + bv.w;
    nrm += y0 * y0 + y1 * y1 + y2 * y2 + y3 * y3;
    us4 o; o.x = f2bf(y0); o.y = f2bf(y1); o.z = f2bf(y2); o.w = f2bf(y3);
    ((us4*)(Y + (size_t)row * C))[i] = o;
  }
  nrm = blk_sum(nrm, red);
  if (threadIdx.x == 0) norms[row] = fmaxf(sqrtf(nrm), 1e-12f);
}

// ------- eff proto: E = proto + LN(T0 [+T1]) -> bf16 + row norm (T fp32) -------
__global__ void ln_add_norm(const float* __restrict__ T0, const float* __restrict__ T1,
                            const float* __restrict__ P,
                            const float* __restrict__ w, const float* __restrict__ b,
                            u16* __restrict__ E, float* __restrict__ norms, int C) {
  __shared__ float red[4];
  int row = blockIdx.x;
  const float* t0 = T0 + (size_t)row * C;
  const float* t1 = T1 ? T1 + (size_t)row * C : nullptr;
  const float* p = P + (size_t)row * C;
  int nv = C >> 2;
  float s = 0.f, ss = 0.f;
  for (int i = threadIdx.x; i < nv; i += 256) {
    float4 v = ((const float4*)t0)[i];
    if (t1) {
      float4 v1 = ((const float4*)t1)[i];
      v.x += v1.x; v.y += v1.y; v.z += v1.z; v.w += v1.w;
    }
    s += v.x + v.y + v.z + v.w;
    ss += v.x * v.x + v.y * v.y + v.z * v.z + v.w * v.w;
  }
  s = blk_sum(s, red);
  ss = blk_sum(ss, red);
  float mean = s / C;
  float inv = rsqrtf(fmaxf(ss / C - mean * mean, 0.f) + 1e-5f);
  float nrm = 0.f;
  for (int i = threadIdx.x; i < nv; i += 256) {
    float4 v = ((const float4*)t0)[i];
    if (t1) {
      float4 v1 = ((const float4*)t1)[i];
      v.x += v1.x; v.y += v1.y; v.z += v1.z; v.w += v1.w;
    }
    float4 pv = ((const float4*)p)[i];
    float4 wv = ((const float4*)w)[i];
    float4 bv = ((const float4*)b)[i];
    float y0 = pv.x + (v.x - mean) * inv * wv.x + bv.x;
    float y1 = pv.y + (v.y - mean) * inv * wv.y + bv.y;
    float y2 = pv.z + (v.z - mean) * inv * wv.z + bv.z;
    float y3 = pv.w + (v.w - mean) * inv * wv.w + bv.w;
    nrm += y0 * y0 + y1 * y1 + y2 * y2 + y3 * y3;
    us4 o; o.x = f2bf(y0); o.y = f2bf(y1); o.z = f2bf(y2); o.w = f2bf(y3);
    ((us4*)(E + (size_t)row * C))[i] = o;
  }
  nrm = blk_sum(nrm, red);
  if (threadIdx.x == 0) norms[row] = fmaxf(sqrtf(nrm), 1e-12f);
}

// ---------------- row L2 norm of a bf16 matrix ----------------
__global__ void rownorm_bf(const u16* __restrict__ X, float* __restrict__ norms, int C) {
  __shared__ float red[4];
  int row = blockIdx.x;
  const us4* x = (const us4*)(X + (size_t)row * C);
  int nv = C >> 2;
  float nrm = 0.f;
  for (int i = threadIdx.x; i < nv; i += 256) {
    us4 v = x[i];
    float a = bf2f(v.x), b = bf2f(v.y), c = bf2f(v.z), d = bf2f(v.w);
    nrm += a * a + b * b + c * c + d * d;
  }
  nrm = blk_sum(nrm, red);
  if (threadIdx.x == 0) norms[row] = fmaxf(sqrtf(nrm), 1e-12f);
}

// --------- fused SPL epilogue, bf16 G[M,2C] (cols 0..C-1 comp, C..2C-1 dots) ---------
template <typename OT>
__global__ void spl_epi_b(const u16* __restrict__ G, const float* __restrict__ bias,
                          const float* __restrict__ gate, const float* __restrict__ rn,
                          const float* __restrict__ cn, const float* __restrict__ resid,
                          OT* __restrict__ out, int C, int relu_out) {
  int r = blockIdx.x;
  int c = (blockIdx.y << 10) + (threadIdx.x << 2);
  const u16* gr = G + (size_t)r * (2 * C);
  us4 cv = *(const us4*)(gr + c);
  us4 dv = *(const us4*)(gr + C + c);
  float4 bv = *(const float4*)(bias + c);
  float4 gv = *(const float4*)(gate + c);
  float4 nv = *(const float4*)(cn + c);
  float rr = rn[r];
  float cf[4] = {bf2f(cv.x), bf2f(cv.y), bf2f(cv.z), bf2f(cv.w)};
  float df[4] = {bf2f(dv.x), bf2f(dv.y), bf2f(dv.z), bf2f(dv.w)};
  float bb[4] = {bv.x, bv.y, bv.z, bv.w};
  float gg[4] = {gv.x, gv.y, gv.z, gv.w};
  float nn[4] = {nv.x, nv.y, nv.z, nv.w};
  float o[4];
#pragma unroll
  for (int j = 0; j < 4; ++j) {
    float sc = df[j] / (rr * nn[j]);
    float v = (cf[j] + bb[j]) * fmaxf(sc - gg[j], 0.f);
    if (relu_out) v = fmaxf(v, 0.f);
    o[j] = v;
  }
  if (resid) {
    float4 rv = *(const float4*)(resid + (size_t)r * C + c);
    o[0] += rv.x; o[1] += rv.y; o[2] += rv.z; o[3] += rv.w;
  }
  if constexpr (sizeof(OT) == 2) {
    us4 ov; ov.x = f2bf(o[0]); ov.y = f2bf(o[1]); ov.z = f2bf(o[2]); ov.w = f2bf(o[3]);
    *(us4*)((u16*)out + (size_t)r * C + c) = ov;
  } else {
    float4 ov = {o[0], o[1], o[2], o[3]};
    *(float4*)((float*)out + (size_t)r * C + c) = ov;
  }
}

// ------ fused SPL epilogue, fp32 partial pair G0,G1 [M,2C]; fp32 out + resid ------
__global__ void spl_epi_p(const float* __restrict__ G0, const float* __restrict__ G1,
                          const float* __restrict__ bias, const float* __restrict__ gate,
                          const float* __restrict__ rn, const float* __restrict__ cn,
                          const float* __restrict__ resid, float* __restrict__ out,
                          int C) {
  int r = blockIdx.x;
  int c = (blockIdx.y << 10) + (threadIdx.x << 2);
  size_t rowb = (size_t)r * (2 * C);
  float4 c0 = *(const float4*)(G0 + rowb + c);
  float4 c1 = *(const float4*)(G1 + rowb + c);
  float4 d0 = *(const float4*)(G0 + rowb + C + c);
  float4 d1 = *(const float4*)(G1 + rowb + C + c);
  float4 bv = *(const float4*)(bias + c);
  float4 gv = *(const float4*)(gate + c);
  float4 nv = *(const float4*)(cn + c);
  float4 rv = *(const float4*)(resid + (size_t)r * C + c);
  float rr = rn[r];
  float cf[4] = {c0.x + c1.x, c0.y + c1.y, c0.z + c1.z, c0.w + c1.w};
  float df[4] = {d0.x + d1.x, d0.y + d1.y, d0.z + d1.z, d0.w + d1.w};
  float bb[4] = {bv.x, bv.y, bv.z, bv.w};
  float gg[4] = {gv.x, gv.y, gv.z, gv.w};
  float nn[4] = {nv.x, nv.y, nv.z, nv.w};
  float re[4] = {rv.x, rv.y, rv.z, rv.w};
  float4 ov;
  float* op = (float*)&ov;
#pragma unroll
  for (int j = 0; j < 4; ++j) {
    float sc = df[j] / (rr * nn[j]);
    op[j] = (cf[j] + bb[j]) * fmaxf(sc - gg[j], 0.f) + re[j];
  }
  *(float4*)(out + (size_t)r * C + c) = ov;
}

// ---------------- RoPE in-place on bf16 m_qkv rows [*, 3072] ----------------
__global__ void rope_ip(u16* __restrict__ MQ, const float* __restrict__ CT_,
                        const float* __restrict__ ST_) {
  long t = (long)blockIdx.x * blockDim.x + threadIdx.x;  // R*512 threads
  int i = (int)(t & 511);
  long row = t >> 9;
  int s = (int)(row & 2047);
  u16* base = MQ + row * 3072;
  float c0 = CT_[(size_t)s * 1024 + i], c1 = CT_[(size_t)s * 1024 + 512 + i];
  float s0 = ST_[(size_t)s * 1024 + i], s1 = ST_[(size_t)s * 1024 + 512 + i];
  float q0 = bf2f(base[i]), q1 = bf2f(base[512 + i]);
  base[i]        = f2bf(q0 * c0 - q1 * s0);
  base[512 + i]  = f2bf(q1 * c1 + q0 * s1);
  float k0 = bf2f(base[1024 + i]), k1 = bf2f(base[1536 + i]);
  base[1024 + i] = f2bf(k0 * c0 - k1 * s0);
  base[1536 + i] = f2bf(k1 * c1 + k0 * s1);
}

// ---------------- V transpose (bf16 m_qkv -> VT[b][d][s]) ----------------
__global__ void vtrans(const u16* __restrict__ MQ, u16* __restrict__ VT) {
  __shared__ u16 tile[32][33];
  int b = blockIdx.z;
  int s0 = blockIdx.x << 5, d0 = blockIdx.y << 5;
  int tx = threadIdx.x, ty = threadIdx.y;
  for (int r = ty; r < 32; r += 8)
    tile[r][tx] = MQ[((size_t)(b * 2048 + s0 + r)) * 3072 + 2048 + d0 + tx];
  __syncthreads();
  for (int r = ty; r < 32; r += 8)
    VT[(size_t)b * 1024 * 2048 + (size_t)(d0 + r) * 2048 + s0 + tx] = tile[tx][r];
}

// ---- causal softmax over [2][2048][2048] scores, scale 1/32 -> bf16 P ----
__global__ void softmax_causal(const float* __restrict__ S, u16* __restrict__ P) {
  __shared__ float red[4];
  int b = blockIdx.x >> 11;
  int q = blockIdx.x & 2047;
  const float* row = S + ((size_t)b << 22) + (size_t)q * 2048;
  u16* prow = P + ((size_t)b << 22) + (size_t)q * 2048;
  int nv = q + 1;
  int base = threadIdx.x * 8;
  float xv[8];
  float4 a = *(const float4*)(row + base);
  float4 bq = *(const float4*)(row + base + 4);
  xv[0] = a.x; xv[1] = a.y; xv[2] = a.z; xv[3] = a.w;
  xv[4] = bq.x; xv[5] = bq.y; xv[6] = bq.z; xv[7] = bq.w;
  float m = -3.4e38f;
#pragma unroll
  for (int j = 0; j < 8; ++j) {
    xv[j] *= 0.03125f;
    if (base + j < nv) m = fmaxf(m, xv[j]);
  }
  m = blk_max(m, red);
  float e[8];
  float ssum = 0.f;
#pragma unroll
  for (int j = 0; j < 8; ++j) {
    e[j] = (base + j < nv) ? __expf(xv[j] - m) : 0.f;
    ssum += e[j];
  }
  ssum = blk_sum(ssum, red);
  float invs = 1.f / ssum;
  us4 o;
  o.x = f2bf(e[0] * invs); o.y = f2bf(e[1] * invs);
  o.z = f2bf(e[2] * invs); o.w = f2bf(e[3] * invs);
  ((us4*)prow)[threadIdx.x * 2] = o;
  o.x = f2bf(e[4] * invs); o.y = f2bf(e[5] * invs);
  o.z = f2bf(e[6] * invs); o.w = f2bf(e[7] * invs);
  ((us4*)prow)[threadIdx.x * 2 + 1] = o;
}

// =============================== launcher ===============================
extern "C" void kernel_launch(void* const* d_in, const int* in_sizes, int n_in,
                              void* d_out, int out_size, void* d_ws, size_t ws_size,
                              hipStream_t stream) {
  (void)in_sizes;
  const float* x         = (const float*)d_in[0];
  const float* cosT      = (const float*)d_in[1];
  const float* sinT      = (const float*)d_in[2];
  const float* ln1_w     = (const float*)d_in[3];
  const float* ln1_b     = (const float*)d_in[4];
  const float* ln2_w     = (const float*)d_in[5];
  const float* ln2_b     = (const float*)d_in[6];
  const float* qkv_mu    = (const float*)d_in[7];
  const float* qkv_proto = (const float*)d_in[8];
  const float* qkv_bias  = (const float*)d_in[9];
  const float* qkv_gate  = (const float*)d_in[10];
  const float* o_mu      = (const float*)d_in[11];
  const float* o_proto   = (const float*)d_in[12];
  const float* o_bias    = (const float*)d_in[13];
  const float* o_gate    = (const float*)d_in[14];
  const float* f1_mu     = (const float*)d_in[15];
  const float* f1_proto  = (const float*)d_in[16];
  const float* f1_bias   = (const float*)d_in[17];
  const float* f1_gate   = (const float*)d_in[18];
  const float* f2_mu     = (const float*)d_in[19];
  const float* f2_proto  = (const float*)d_in[20];
  const float* f2_bias   = (const float*)d_in[21];
  const float* f2_gate   = (const float*)d_in[22];
  const float* pt_qkv    = (const float*)d_in[23];
  const float* pt_o      = (const float*)d_in[24];
  const float* pt_f1     = (const float*)d_in[25];
  const float* pt_f2     = (const float*)d_in[26];
  const float* pln_qkv_w = (const float*)d_in[27];
  const float* pln_qkv_b = (const float*)d_in[28];
  const float* pln_o_w   = (const float*)d_in[29];
  const float* pln_o_b   = (const float*)d_in[30];
  const float* pln_f1_w  = (const float*)d_in[31];
  const float* pln_f1_b  = (const float*)d_in[32];
  const float* pln_f2_w  = (const float*)d_in[33];
  const float* pln_f2_b  = (const float*)d_in[34];
  const float* prev_qkv  = (const float*)d_in[35];
  const float* prev_o    = (const float*)d_in[36];
  const float* prev_f1   = (const float*)d_in[37];
  const float* prev_f2   = (const float*)d_in[38];

  const long D = 1024, TD = 3072, FD = 4096, R = 4096;

  char* W = (char*)d_ws;
  size_t off = 0;
  auto alloc = [&](size_t bytes) {
    void* p = W + off;
    off = (off + bytes + 255) & ~(size_t)255;
    return p;
  };
  char* GOUT = (char*)alloc(67108864);   // fused GEMM out / phase-1 staging / scores+P
  u16*  RC   = (u16*)alloc(33554432);    // m_qkv (phase 2-3) / h (phase 5) / f2-proto partials
  u16*  wq   = (u16*)alloc(2 * TD * D * 2);   // [mu_qkv; eff_qkv]
  u16*  wo   = (u16*)alloc(2 * D * D * 2);
  u16*  wf1  = (u16*)alloc(2 * FD * D * 2);
  u16*  wf2  = (u16*)alloc(2 * D * FD * 2);
  float* X1  = (float*)alloc(R * D * 4);
  float* SC  = (float*)alloc(R * D * 4);      // proto T fp32 (max 4096x1024)
  u16*  P1   = (u16*)alloc(R * D * 2);        // attn_in / ffn_in bf16
  u16*  VT   = (u16*)alloc(2 * D * 2048 * 2);
  u16*  AOB  = (u16*)alloc(R * D * 2);
  float* pnq     = (float*)alloc(TD * 4);
  float* pno     = (float*)alloc(D * 4);
  float* pnf1    = (float*)alloc(FD * 4);
  float* pnf2    = (float*)alloc(D * 4);
  float* rn_ain  = (float*)alloc(R * 4);
  float* rn_aout = (float*)alloc(R * 4);
  float* rn_ffn  = (float*)alloc(R * 4);
  float* rn_h    = (float*)alloc(R * 4);
  size_t need = off;

  if (n_in < 39 || need > ws_size) {
    long n = out_size;
    fillv<<<dim3((unsigned)((n + 255) / 256)), 256, 0, stream>>>((float*)d_out, n, 12345.0f);
    return;
  }

  // overlays inside GOUT
  u16* SA = (u16*)GOUT;                       // phase-1 prev staging (<=8MiB)
  u16* SB = (u16*)(GOUT + 33554432);          // phase-1 pt staging (<=32MiB)
  float* SCORES = (float*)GOUT;               // [2][2048][2048] fp32 (32MiB)
  u16* PB = (u16*)(GOUT + 33554432);          // [2][2048][2048] bf16 (16MiB)

  auto cvt = [&](const float* s, u16* d, long n) {
    long n4 = n >> 2;
    cvt_bf16<<<dim3((unsigned)((n4 + 255) / 256)), 256, 0, stream>>>(s, d, n4);
  };

  // ---- phase 1: effective protos ----
  struct Proto { const float* prev; const float* pt; const float* proto;
                 const float* w; const float* b; u16* wbuf; float* pn;
                 int M; int N; int K; };
  Proto protos[4] = {
    {prev_qkv, pt_qkv, qkv_proto, pln_qkv_w, pln_qkv_b, wq,  pnq,  3072, 1024, 1024},
    {prev_o,   pt_o,   o_proto,   pln_o_w,   pln_o_b,   wo,  pno,  1024, 1024, 1024},
    {prev_f1,  pt_f1,  f1_proto,  pln_f1_w,  pln_f1_b,  wf1, pnf1, 4096, 1024, 1024},
    {prev_f2,  pt_f2,  f2_proto,  pln_f2_w,  pln_f2_b,  wf2, pnf2, 1024, 4096, 4096},
  };
  for (int p = 0; p < 4; ++p) {
    Proto& pr = protos[p];
    u16* eff = pr.wbuf + (size_t)pr.M * pr.N;   // second half of stacked buffer
    cvt(pr.prev, SA, (long)pr.M * pr.K);
    cvt(pr.pt,   SB, (long)pr.N * pr.K);
    if (pr.K == 4096) {
      // split-K x2, fp32 partials in RC
      float* T0 = (float*)RC;
      float* T1 = T0 + (size_t)pr.M * pr.N;
      gemm_bt<float><<<dim3(pr.M / 128, pr.N / 128, 2), 256, 0, stream>>>(
          SA, SB, T0, pr.M, pr.N, pr.K, pr.K, pr.K, 1, 0, 0, 0);
      ln_add_norm<<<pr.M, 256, 0, stream>>>(T0, T1, pr.proto, pr.w, pr.b, eff, pr.pn, pr.N);
    } else {
      gemm_bt<float><<<dim3(pr.M / 128, pr.N / 128, 1), 256, 0, stream>>>(
          SA, SB, SC, pr.M, pr.N, pr.K, pr.K, pr.K, 0, 0, 0, 0);
      ln_add_norm<<<pr.M, 256, 0, stream>>>(SC, nullptr, pr.proto, pr.w, pr.b, eff, pr.pn, pr.N);
    }
  }
  cvt(qkv_mu, wq, TD * D);
  cvt(o_mu,   wo, D * D);
  cvt(f1_mu,  wf1, FD * D);
  cvt(f2_mu,  wf2, D * FD);

  // ---- phase 2: attention input LN + fused qkv SPL ----
  ln_rows<<<4096, 256, 0, stream>>>(x, ln1_w, ln1_b, P1, rn_ain, 1024);
  gemm_bt<u16><<<dim3(32, 48, 1), 256, 0, stream>>>(
      P1, wq, (u16*)GOUT, 4096, 6144, 1024, 1024, 1024, 0, 0, 0, 0);
  spl_epi_b<u16><<<dim3(4096, 3), 256, 0, stream>>>(
      (u16*)GOUT, qkv_bias, qkv_gate, rn_ain, pnq, nullptr, RC, 3072, 0);

  // ---- phase 3: RoPE + attention (batched) ----
  rope_ip<<<dim3((unsigned)((R * 512) / 256)), 256, 0, stream>>>(RC, cosT, sinT);
  vtrans<<<dim3(64, 32, 2), dim3(32, 8), 0, stream>>>(RC, VT);
  // QK^T causal: 136 lower-triangle tiles x 2 batches
  gemm_bt<float><<<dim3(136, 1, 2), 256, 0, stream>>>(
      RC, RC + 1024, SCORES, 2048, 2048, 1024, 3072, 3072,
      3, 2048L * 3072, 2048L * 3072, 1L << 22);
  softmax_causal<<<4096, 256, 0, stream>>>(SCORES, PB);
  gemm_bt<u16><<<dim3(16, 8, 2), 256, 0, stream>>>(
      PB, VT, AOB, 2048, 1024, 2048, 2048, 2048,
      2, 1L << 22, 1024L * 2048, 2048L * 1024);
  rownorm_bf<<<4096, 256, 0, stream>>>(AOB, rn_aout, 1024);

  // ---- phase 4: fused o SPL + residual -> X1 (fp32) ----
  gemm_bt<u16><<<dim3(32, 16, 1), 256, 0, stream>>>(
      AOB, wo, (u16*)GOUT, 4096, 2048, 1024, 1024, 1024, 0, 0, 0, 0);
  spl_epi_b<float><<<dim3(4096, 1), 256, 0, stream>>>(
      (u16*)GOUT, o_bias, o_gate, rn_aout, pno, x, X1, 1024, 0);

  // ---- phase 5: FFN ----
  ln_rows<<<4096, 256, 0, stream>>>(X1, ln2_w, ln2_b, P1, rn_ffn, 1024);
  gemm_bt<u16><<<dim3(32, 64, 1), 256, 0, stream>>>(
      P1, wf1, (u16*)GOUT, 4096, 8192, 1024, 1024, 1024, 0, 0, 0, 0);
  spl_epi_b<u16><<<dim3(4096, 4), 256, 0, stream>>>(
      (u16*)GOUT, f1_bias, f1_gate, rn_ffn, pnf1, nullptr, RC, 4096, 1);  // h -> RC
  rownorm_bf<<<4096, 256, 0, stream>>>(RC, rn_h, 4096);
  // f2 fused, split-K x2: partials [2][4096][2048] fp32 = 64 MiB in GOUT
  gemm_bt<float><<<dim3(32, 16, 2), 256, 0, stream>>>(
      RC, wf2, (float*)GOUT, 4096, 2048, 4096, 4096, 4096, 1, 0, 0, 0);
  spl_epi_p<<<dim3(4096, 1), 256, 0, stream>>>(
      (float*)GOUT, (float*)GOUT + 4096L * 2048, f2_bias, f2_gate, rn_h, pnf2,
      X1, (float*)d_out, 1024);
}

// Round 4
// 595.992 us; speedup vs baseline: 1.4642x; 1.1126x over previous
//
#include <hip/hip_runtime.h>
#include <cstdint>

typedef unsigned short u16;
typedef __attribute__((ext_vector_type(8))) short sh8;   // 8 bf16 (4 VGPRs)
typedef __attribute__((ext_vector_type(4))) float f32x4;

struct __align__(8) us4 { u16 x, y, z, w; };

__device__ __forceinline__ u16 f2bf(float f) {
  unsigned u = __float_as_uint(f);
  u += 0x7FFFu + ((u >> 16) & 1u);   // RNE
  return (u16)(u >> 16);
}
__device__ __forceinline__ float bf2f(u16 h) {
  return __uint_as_float((unsigned)h << 16);
}

// ---------------- block reductions (blockDim.x == 256) ----------------
__device__ __forceinline__ float blk_sum(float v, float* red) {
#pragma unroll
  for (int o = 32; o; o >>= 1) v += __shfl_xor(v, o);
  __syncthreads();
  if ((threadIdx.x & 63) == 0) red[threadIdx.x >> 6] = v;
  __syncthreads();
  return red[0] + red[1] + red[2] + red[3];
}
__device__ __forceinline__ float blk_max(float v, float* red) {
#pragma unroll
  for (int o = 32; o; o >>= 1) v = fmaxf(v, __shfl_xor(v, o));
  __syncthreads();
  if ((threadIdx.x & 63) == 0) red[threadIdx.x >> 6] = v;
  __syncthreads();
  return fmaxf(fmaxf(red[0], red[1]), fmaxf(red[2], red[3]));
}

// ---------------- fp32 -> bf16 ----------------
__global__ void cvt_bf16(const float* __restrict__ S, u16* __restrict__ D, long n4) {
  long i = (long)blockIdx.x * blockDim.x + threadIdx.x;
  if (i >= n4) return;
  float4 v = ((const float4*)S)[i];
  us4 o; o.x = f2bf(v.x); o.y = f2bf(v.y); o.z = f2bf(v.z); o.w = f2bf(v.w);
  ((us4*)D)[i] = o;
}

__global__ void fillv(float* __restrict__ o, long n, float v) {
  long i = (long)blockIdx.x * blockDim.x + threadIdx.x;
  if (i < n) o[i] = v;
}

// ---------------- bf16 GEMM: C[M,N] = A[M,K] @ B[N,K]^T ----------------
// m97 structure: 128x128 tile, BK=32, 4 waves (64x64 each), global_load_lds w16.
// mode 0: plain 2D grid
// mode 1: split-K over blockIdx.z; C gets per-chunk partials at stride M*N
// mode 2: batched over z (strides zsA/zsB/zsC)
// mode 3: batched + causal lower-triangle tile enumeration on blockIdx.x
// mode 4: batched + causal K-cap (k0e = (bm+1)*128)  [PV]
// mode 5: multi-M batched: Mz packed 16b/z in zsB, B z-stride 2^20, A/C via zsA/zsC
template <typename CT>
__global__ __launch_bounds__(256, 2) void gemm_bt(
    const u16* __restrict__ A, const u16* __restrict__ B, CT* __restrict__ C,
    int M, int N, int K, int lda, int ldb,
    int mode, long zsA, long zsB, long zsC) {
  int bm, bn;
  int z = blockIdx.z;
  if (mode == 3) {
    int t = blockIdx.x;
    int m = (int)floorf((sqrtf(8.f * t + 1.f) - 1.f) * 0.5f);
    while ((m + 1) * (m + 2) / 2 <= t) ++m;
    while (m * (m + 1) / 2 > t) --m;
    bm = m; bn = t - m * (m + 1) / 2;
  } else {
    bm = blockIdx.x; bn = blockIdx.y;
  }
  int k0s = 0, k0e = K;
  if (mode == 1) {
    int kc = K / gridDim.z;
    k0s = z * kc; k0e = k0s + kc;
    C += (size_t)z * M * (size_t)N;
  } else if (mode == 2 || mode == 3) {
    A += (size_t)z * zsA; B += (size_t)z * zsB; C += (size_t)z * zsC;
  } else if (mode == 4) {
    A += (size_t)z * zsA; B += (size_t)z * zsB; C += (size_t)z * zsC;
    k0e = (bm + 1) * 128;
  } else if (mode == 5) {
    int Mz = (int)((zsB >> (z * 16)) & 0xFFFF);
    if (bm * 128 >= Mz) return;
    A += (size_t)z * zsA; B += (size_t)z * 1048576; C += (size_t)z * zsC;
  }

  __shared__ __align__(16) u16 As[128 * 32];
  __shared__ __align__(16) u16 Bs[128 * 32];
  int tid = threadIdx.x, wid = tid >> 6, lane = tid & 63;
  int wr = (wid >> 1) << 6, wc = (wid & 1) << 6;
  int lr = lane & 15, lk = (lane >> 4) << 3;

  f32x4 acc[4][4];
  const f32x4 zf = {0.f, 0.f, 0.f, 0.f};
#pragma unroll
  for (int i = 0; i < 4; ++i)
#pragma unroll
    for (int j = 0; j < 4; ++j) acc[i][j] = zf;

  int r0 = tid >> 2, c0 = (tid & 3) << 3;
  const size_t baseA = (size_t)bm * 128, baseB = (size_t)bn * 128;
  const u16* Ab = A + baseA * lda;
  const u16* Bp = B + baseB * ldb;

  for (int k0 = k0s; k0 < k0e; k0 += 32) {
    __builtin_amdgcn_global_load_lds(
        (const __attribute__((address_space(1))) void*)(Ab + (size_t)r0 * lda + k0 + c0),
        (__attribute__((address_space(3))) void*)(As + (wid << 9)), 16, 0, 0);
    __builtin_amdgcn_global_load_lds(
        (const __attribute__((address_space(1))) void*)(Ab + (size_t)(64 + r0) * lda + k0 + c0),
        (__attribute__((address_space(3))) void*)(As + 2048 + (wid << 9)), 16, 0, 0);
    __builtin_amdgcn_global_load_lds(
        (const __attribute__((address_space(1))) void*)(Bp + (size_t)r0 * ldb + k0 + c0),
        (__attribute__((address_space(3))) void*)(Bs + (wid << 9)), 16, 0, 0);
    __builtin_amdgcn_global_load_lds(
        (const __attribute__((address_space(1))) void*)(Bp + (size_t)(64 + r0) * ldb + k0 + c0),
        (__attribute__((address_space(3))) void*)(Bs + 2048 + (wid << 9)), 16, 0, 0);
    __syncthreads();
    sh8 af[4], bfr[4];
#pragma unroll
    for (int f = 0; f < 4; ++f) {
      af[f]  = *(const sh8*)(As + (wr + f * 16 + lr) * 32 + lk);
      bfr[f] = *(const sh8*)(Bs + (wc + f * 16 + lr) * 32 + lk);
    }
#pragma unroll
    for (int i = 0; i < 4; ++i)
#pragma unroll
      for (int j = 0; j < 4; ++j)
        acc[i][j] = __builtin_amdgcn_mfma_f32_16x16x32_bf16(af[i], bfr[j], acc[i][j], 0, 0, 0);
    __syncthreads();
  }

  // C/D layout (m89): col = lane&15, row = (lane>>4)*4 + reg
  int cr = (lane >> 4) << 2, cc = lane & 15;
#pragma unroll
  for (int i = 0; i < 4; ++i)
#pragma unroll
    for (int j = 0; j < 4; ++j) {
      size_t cb = (baseA + wr + i * 16 + cr) * (size_t)N + (baseB + wc + j * 16 + cc);
#pragma unroll
      for (int r = 0; r < 4; ++r) {
        float v = acc[i][j][r];
        if constexpr (sizeof(CT) == 2) C[cb + (size_t)r * N] = (CT)f2bf(v);
        else                           C[cb + (size_t)r * N] = v;
      }
    }
}

// ---------------- row LayerNorm (fp32 in) -> bf16 out + row L2 norm ----------------
__global__ void ln_rows(const float* __restrict__ X, const float* __restrict__ w,
                        const float* __restrict__ b, u16* __restrict__ Y,
                        float* __restrict__ norms, int C) {
  __shared__ float red[4];
  int row = blockIdx.x;
  const float* x = X + (size_t)row * C;
  int nv = C >> 2;
  float s = 0.f, ss = 0.f;
  for (int i = threadIdx.x; i < nv; i += 256) {
    float4 v = ((const float4*)x)[i];
    s += v.x + v.y + v.z + v.w;
    ss += v.x * v.x + v.y * v.y + v.z * v.z + v.w * v.w;
  }
  s = blk_sum(s, red);
  ss = blk_sum(ss, red);
  float mean = s / C;
  float inv = rsqrtf(fmaxf(ss / C - mean * mean, 0.f) + 1e-5f);
  float nrm = 0.f;
  for (int i = threadIdx.x; i < nv; i += 256) {
    float4 v = ((const float4*)x)[i];
    float4 wv = ((const float4*)w)[i];
    float4 bv = ((const float4*)b)[i];
    float y0 = (v.x - mean) * inv * wv.x + bv.x;
    float y1 = (v.y - mean) * inv * wv.y + bv.y;
    float y2 = (v.z - mean) * inv * wv.z + bv.z;
    float y3 = (v.w - mean) * inv * wv.w + bv.w;
    nrm += y0 * y0 + y1 * y1 + y2 * y2 + y3 * y3;
    us4 o; o.x = f2bf(y0); o.y = f2bf(y1); o.z = f2bf(y2); o.w = f2bf(y3);
    ((us4*)(Y + (size_t)row * C))[i] = o;
  }
  nrm = blk_sum(nrm, red);
  if (threadIdx.x == 0) norms[row] = fmaxf(sqrtf(nrm), 1e-12f);
}

// ------- eff proto: E = proto + LN(T0 [+T1]) -> bf16 + row norm (T bf16) -------
__global__ void ln_add_norm(const u16* __restrict__ T0, const u16* __restrict__ T1,
                            const float* __restrict__ P,
                            const float* __restrict__ w, const float* __restrict__ b,
                            u16* __restrict__ E, float* __restrict__ norms, int C) {
  __shared__ float red[4];
  int row = blockIdx.x;
  const us4* t0 = (const us4*)(T0 + (size_t)row * C);
  const us4* t1 = T1 ? (const us4*)(T1 + (size_t)row * C) : nullptr;
  const float* p = P + (size_t)row * C;
  int nv = C >> 2;
  float s = 0.f, ss = 0.f;
  for (int i = threadIdx.x; i < nv; i += 256) {
    us4 v = t0[i];
    float f0 = bf2f(v.x), f1 = bf2f(v.y), f2 = bf2f(v.z), f3 = bf2f(v.w);
    if (t1) {
      us4 v1 = t1[i];
      f0 += bf2f(v1.x); f1 += bf2f(v1.y); f2 += bf2f(v1.z); f3 += bf2f(v1.w);
    }
    s += f0 + f1 + f2 + f3;
    ss += f0 * f0 + f1 * f1 + f2 * f2 + f3 * f3;
  }
  s = blk_sum(s, red);
  ss = blk_sum(ss, red);
  float mean = s / C;
  float inv = rsqrtf(fmaxf(ss / C - mean * mean, 0.f) + 1e-5f);
  float nrm = 0.f;
  for (int i = threadIdx.x; i < nv; i += 256) {
    us4 v = t0[i];
    float f0 = bf2f(v.x), f1 = bf2f(v.y), f2 = bf2f(v.z), f3 = bf2f(v.w);
    if (t1) {
      us4 v1 = t1[i];
      f0 += bf2f(v1.x); f1 += bf2f(v1.y); f2 += bf2f(v1.z); f3 += bf2f(v1.w);
    }
    float4 pv = ((const float4*)p)[i];
    float4 wv = ((const float4*)w)[i];
    float4 bv = ((const float4*)b)[i];
    float y0 = pv.x + (f0 - mean) * inv * wv.x + bv.x;
    float y1 = pv.y + (f1 - mean) * inv * wv.y + bv.y;
    float y2 = pv.z + (f2 - mean) * inv * wv.z + bv.z;
    float y3 = pv.w + (f3 - mean) * inv * wv.w + bv.w;
    nrm += y0 * y0 + y1 * y1 + y2 * y2 + y3 * y3;
    us4 o; o.x = f2bf(y0); o.y = f2bf(y1); o.z = f2bf(y2); o.w = f2bf(y3);
    ((us4*)(E + (size_t)row * C))[i] = o;
  }
  nrm = blk_sum(nrm, red);
  if (threadIdx.x == 0) norms[row] = fmaxf(sqrtf(nrm), 1e-12f);
}

// ---------------- row L2 norm of a bf16 matrix ----------------
__global__ void rownorm_bf(const u16* __restrict__ X, float* __restrict__ norms, int C) {
  __shared__ float red[4];
  int row = blockIdx.x;
  const us4* x = (const us4*)(X + (size_t)row * C);
  int nv = C >> 2;
  float nrm = 0.f;
  for (int i = threadIdx.x; i < nv; i += 256) {
    us4 v = x[i];
    float a = bf2f(v.x), b = bf2f(v.y), c = bf2f(v.z), d = bf2f(v.w);
    nrm += a * a + b * b + c * c + d * d;
  }
  nrm = blk_sum(nrm, red);
  if (threadIdx.x == 0) norms[row] = fmaxf(sqrtf(nrm), 1e-12f);
}

// ---- SPL epilogue core: o[j] for us4 at column c of stacked G row (width 2C) ----
__device__ __forceinline__ void epi4(const u16* gr, int C, int c, float rr,
                                     const float* bias, const float* gate,
                                     const float* cn, float* o) {
  us4 cv = *(const us4*)(gr + c);
  us4 dv = *(const us4*)(gr + C + c);
  float4 bv = *(const float4*)(bias + c);
  float4 gv = *(const float4*)(gate + c);
  float4 nv = *(const float4*)(cn + c);
  float cf[4] = {bf2f(cv.x), bf2f(cv.y), bf2f(cv.z), bf2f(cv.w)};
  float df[4] = {bf2f(dv.x), bf2f(dv.y), bf2f(dv.z), bf2f(dv.w)};
  float bb[4] = {bv.x, bv.y, bv.z, bv.w};
  float gg[4] = {gv.x, gv.y, gv.z, gv.w};
  float nn[4] = {nv.x, nv.y, nv.z, nv.w};
#pragma unroll
  for (int j = 0; j < 4; ++j) {
    float sc = df[j] / (rr * nn[j]);
    o[j] = (cf[j] + bb[j]) * fmaxf(sc - gg[j], 0.f);
  }
}

// --------- fused qkv SPL epilogue + RoPE, one block per row ----------
// G[r] = [comp(3072) | dots(3072)] bf16; out m_qkv row (q,k roped; v plain).
__global__ void spl_rope_row(const u16* __restrict__ G, const float* __restrict__ bias,
                             const float* __restrict__ gate, const float* __restrict__ rn,
                             const float* __restrict__ cn, const float* __restrict__ CT_,
                             const float* __restrict__ ST_, u16* __restrict__ MQ) {
  int r = blockIdx.x;
  int s = r & 2047;
  const u16* gr = G + (size_t)r * 6144;
  u16* outr = MQ + (size_t)r * 3072;
  float rr = rn[r];
  int t = threadIdx.x;

  // q (threads 0-127) / k (threads 128-255): pairs (c, c+512)
  int qk = (t >> 7);              // 0 = q, 1 = k
  int c = qk * 1024 + ((t & 127) << 2);
  int d = c - qk * 1024;          // position within the 1024-wide head
  float a0[4], a1[4];
  epi4(gr, 3072, c, rr, bias, gate, cn, a0);
  epi4(gr, 3072, c + 512, rr, bias, gate, cn, a1);
  const float* ct = CT_ + (size_t)s * 1024;
  const float* st = ST_ + (size_t)s * 1024;
  float4 c0 = *(const float4*)(ct + d);
  float4 s0 = *(const float4*)(st + d);
  float4 c1 = *(const float4*)(ct + d + 512);
  float4 s1 = *(const float4*)(st + d + 512);
  float cc0[4] = {c0.x, c0.y, c0.z, c0.w}, ss0[4] = {s0.x, s0.y, s0.z, s0.w};
  float cc1[4] = {c1.x, c1.y, c1.z, c1.w}, ss1[4] = {s1.x, s1.y, s1.z, s1.w};
  us4 o0, o1;
  o0.x = f2bf(a0[0] * cc0[0] - a1[0] * ss0[0]);
  o0.y = f2bf(a0[1] * cc0[1] - a1[1] * ss0[1]);
  o0.z = f2bf(a0[2] * cc0[2] - a1[2] * ss0[2]);
  o0.w = f2bf(a0[3] * cc0[3] - a1[3] * ss0[3]);
  o1.x = f2bf(a1[0] * cc1[0] + a0[0] * ss1[0]);
  o1.y = f2bf(a1[1] * cc1[1] + a0[1] * ss1[1]);
  o1.z = f2bf(a1[2] * cc1[2] + a0[2] * ss1[2]);
  o1.w = f2bf(a1[3] * cc1[3] + a0[3] * ss1[3]);
  *(us4*)(outr + c) = o0;
  *(us4*)(outr + c + 512) = o1;

  // v: cols 2048..3071 (all 256 threads x 4)
  int cv_ = 2048 + (t << 2);
  float vv[4];
  epi4(gr, 3072, cv_, rr, bias, gate, cn, vv);
  us4 ov; ov.x = f2bf(vv[0]); ov.y = f2bf(vv[1]); ov.z = f2bf(vv[2]); ov.w = f2bf(vv[3]);
  *(us4*)(outr + cv_) = ov;
}

// --------- fused f1 SPL epilogue (relu) + row norm of h, one block per row ---------
__global__ void spl_f1_row(const u16* __restrict__ G, const float* __restrict__ bias,
                           const float* __restrict__ gate, const float* __restrict__ rn,
                           const float* __restrict__ cn, u16* __restrict__ H,
                           float* __restrict__ rn_h) {
  __shared__ float red[4];
  int r = blockIdx.x;
  const u16* gr = G + (size_t)r * 8192;
  u16* hr = H + (size_t)r * 4096;
  float rr = rn[r];
  float nrm = 0.f;
  for (int c = threadIdx.x << 2; c < 4096; c += 1024) {
    float o[4];
    epi4(gr, 4096, c, rr, bias, gate, cn, o);
#pragma unroll
    for (int j = 0; j < 4; ++j) {
      o[j] = fmaxf(o[j], 0.f);
      nrm += o[j] * o[j];
    }
    us4 ov; ov.x = f2bf(o[0]); ov.y = f2bf(o[1]); ov.z = f2bf(o[2]); ov.w = f2bf(o[3]);
    *(us4*)(hr + c) = ov;
  }
  nrm = blk_sum(nrm, red);
  if (threadIdx.x == 0) rn_h[r] = fmaxf(sqrtf(nrm), 1e-12f);
}

// --- fused o SPL + residual -> X1 (fp32), then LN2 -> bf16 + rn_ffn, one block/row ---
__global__ void spl_o_ln_row(const u16* __restrict__ G, const float* __restrict__ bias,
                             const float* __restrict__ gate, const float* __restrict__ rn,
                             const float* __restrict__ cn, const float* __restrict__ xres,
                             const float* __restrict__ lw, const float* __restrict__ lb,
                             float* __restrict__ X1, u16* __restrict__ Y,
                             float* __restrict__ rn_ffn) {
  __shared__ float red[4];
  int r = blockIdx.x;
  int c = threadIdx.x << 2;
  const u16* gr = G + (size_t)r * 2048;
  float o[4];
  epi4(gr, 1024, c, rn[r], bias, gate, cn, o);
  float4 rv = *(const float4*)(xres + (size_t)r * 1024 + c);
  o[0] += rv.x; o[1] += rv.y; o[2] += rv.z; o[3] += rv.w;
  float4 xo = {o[0], o[1], o[2], o[3]};
  *(float4*)(X1 + (size_t)r * 1024 + c) = xo;
  float s = o[0] + o[1] + o[2] + o[3];
  float ss = o[0] * o[0] + o[1] * o[1] + o[2] * o[2] + o[3] * o[3];
  s = blk_sum(s, red);
  ss = blk_sum(ss, red);
  float mean = s * (1.f / 1024.f);
  float inv = rsqrtf(fmaxf(ss * (1.f / 1024.f) - mean * mean, 0.f) + 1e-5f);
  float4 wv = *(const float4*)(lw + c);
  float4 bv = *(const float4*)(lb + c);
  float ww[4] = {wv.x, wv.y, wv.z, wv.w}, bb[4] = {bv.x, bv.y, bv.z, bv.w};
  float nrm = 0.f;
  us4 ov;
  u16* op = (u16*)&ov;
#pragma unroll
  for (int j = 0; j < 4; ++j) {
    float y = (o[j] - mean) * inv * ww[j] + bb[j];
    nrm += y * y;
    op[j] = f2bf(y);
  }
  *(us4*)(Y + (size_t)r * 1024 + c) = ov;
  nrm = blk_sum(nrm, red);
  if (threadIdx.x == 0) rn_ffn[r] = fmaxf(sqrtf(nrm), 1e-12f);
}

// ------ final SPL epilogue: bf16 split-K partial pair + residual -> fp32 out ------
__global__ void spl_epi_p(const u16* __restrict__ G0, const u16* __restrict__ G1,
                          const float* __restrict__ bias, const float* __restrict__ gate,
                          const float* __restrict__ rn, const float* __restrict__ cn,
                          const float* __restrict__ resid, float* __restrict__ out) {
  int r = blockIdx.x;
  int c = threadIdx.x << 2;
  size_t rowb = (size_t)r * 2048;
  us4 c0 = *(const us4*)(G0 + rowb + c);
  us4 c1 = *(const us4*)(G1 + rowb + c);
  us4 d0 = *(const us4*)(G0 + rowb + 1024 + c);
  us4 d1 = *(const us4*)(G1 + rowb + 1024 + c);
  float4 bv = *(const float4*)(bias + c);
  float4 gv = *(const float4*)(gate + c);
  float4 nv = *(const float4*)(cn + c);
  float4 rv = *(const float4*)(resid + (size_t)r * 1024 + c);
  float rr = rn[r];
  float cf[4] = {bf2f(c0.x) + bf2f(c1.x), bf2f(c0.y) + bf2f(c1.y),
                 bf2f(c0.z) + bf2f(c1.z), bf2f(c0.w) + bf2f(c1.w)};
  float df[4] = {bf2f(d0.x) + bf2f(d1.x), bf2f(d0.y) + bf2f(d1.y),
                 bf2f(d0.z) + bf2f(d1.z), bf2f(d0.w) + bf2f(d1.w)};
  float bb[4] = {bv.x, bv.y, bv.z, bv.w};
  float gg[4] = {gv.x, gv.y, gv.z, gv.w};
  float nn[4] = {nv.x, nv.y, nv.z, nv.w};
  float re[4] = {rv.x, rv.y, rv.z, rv.w};
  float4 ov;
  float* op = (float*)&ov;
#pragma unroll
  for (int j = 0; j < 4; ++j) {
    float sc = df[j] / (rr * nn[j]);
    op[j] = (cf[j] + bb[j]) * fmaxf(sc - gg[j], 0.f) + re[j];
  }
  *(float4*)(out + (size_t)r * 1024 + c) = ov;
}

// ---------------- V transpose (bf16 m_qkv -> VT[b][d][s]) ----------------
__global__ void vtrans(const u16* __restrict__ MQ, u16* __restrict__ VT) {
  __shared__ u16 tile[32][33];
  int b = blockIdx.z;
  int s0 = blockIdx.x << 5, d0 = blockIdx.y << 5;
  int tx = threadIdx.x, ty = threadIdx.y;
  for (int r = ty; r < 32; r += 8)
    tile[r][tx] = MQ[((size_t)(b * 2048 + s0 + r)) * 3072 + 2048 + d0 + tx];
  __syncthreads();
  for (int r = ty; r < 32; r += 8)
    VT[(size_t)b * 1024 * 2048 + (size_t)(d0 + r) * 2048 + s0 + tx] = tile[tx][r];
}

// ---- causal softmax over [2][2048][2048] scores, scale 1/32 -> bf16 P ----
// Skips fully-masked loads; writes only up to the row's 128-tile cap.
__global__ void softmax_causal(const float* __restrict__ S, u16* __restrict__ P) {
  __shared__ float red[4];
  int b = blockIdx.x >> 11;
  int q = blockIdx.x & 2047;
  const float* row = S + ((size_t)b << 22) + (size_t)q * 2048;
  u16* prow = P + ((size_t)b << 22) + (size_t)q * 2048;
  int nv = q + 1;
  int wcap = ((q >> 7) + 1) << 7;
  int base = threadIdx.x * 8;
  float e[8];
  float m = -3.4e38f;
  float xv[8];
  bool live = base < nv;
  if (live) {
    float4 a = *(const float4*)(row + base);
    float4 bq = *(const float4*)(row + base + 4);
    xv[0] = a.x; xv[1] = a.y; xv[2] = a.z; xv[3] = a.w;
    xv[4] = bq.x; xv[5] = bq.y; xv[6] = bq.z; xv[7] = bq.w;
#pragma unroll
    for (int j = 0; j < 8; ++j) {
      xv[j] *= 0.03125f;
      if (base + j < nv) m = fmaxf(m, xv[j]);
    }
  }
  m = blk_max(m, red);
  float ssum = 0.f;
#pragma unroll
  for (int j = 0; j < 8; ++j) {
    e[j] = (live && base + j < nv) ? __expf(xv[j] - m) : 0.f;
    ssum += e[j];
  }
  ssum = blk_sum(ssum, red);
  float invs = 1.f / ssum;
  if (base < wcap) {
    us4 o;
    o.x = f2bf(e[0] * invs); o.y = f2bf(e[1] * invs);
    o.z = f2bf(e[2] * invs); o.w = f2bf(e[3] * invs);
    ((us4*)prow)[threadIdx.x * 2] = o;
    o.x = f2bf(e[4] * invs); o.y = f2bf(e[5] * invs);
    o.z = f2bf(e[6] * invs); o.w = f2bf(e[7] * invs);
    ((us4*)prow)[threadIdx.x * 2 + 1] = o;
  }
}

// =============================== launcher ===============================
extern "C" void kernel_launch(void* const* d_in, const int* in_sizes, int n_in,
                              void* d_out, int out_size, void* d_ws, size_t ws_size,
                              hipStream_t stream) {
  (void)in_sizes;
  const float* x         = (const float*)d_in[0];
  const float* cosT      = (const float*)d_in[1];
  const float* sinT      = (const float*)d_in[2];
  const float* ln1_w     = (const float*)d_in[3];
  const float* ln1_b     = (const float*)d_in[4];
  const float* ln2_w     = (const float*)d_in[5];
  const float* ln2_b     = (const float*)d_in[6];
  const float* qkv_mu    = (const float*)d_in[7];
  const float* qkv_proto = (const float*)d_in[8];
  const float* qkv_bias  = (const float*)d_in[9];
  const float* qkv_gate  = (const float*)d_in[10];
  const float* o_mu      = (const float*)d_in[11];
  const float* o_proto   = (const float*)d_in[12];
  const float* o_bias    = (const float*)d_in[13];
  const float* o_gate    = (const float*)d_in[14];
  const float* f1_mu     = (const float*)d_in[15];
  const float* f1_proto  = (const float*)d_in[16];
  const float* f1_bias   = (const float*)d_in[17];
  const float* f1_gate   = (const float*)d_in[18];
  const float* f2_mu     = (const float*)d_in[19];
  const float* f2_proto  = (const float*)d_in[20];
  const float* f2_bias   = (const float*)d_in[21];
  const float* f2_gate   = (const float*)d_in[22];
  const float* pt_qkv    = (const float*)d_in[23];
  const float* pt_o      = (const float*)d_in[24];
  const float* pt_f1     = (const float*)d_in[25];
  const float* pt_f2     = (const float*)d_in[26];
  const float* pln_qkv_w = (const float*)d_in[27];
  const float* pln_qkv_b = (const float*)d_in[28];
  const float* pln_o_w   = (const float*)d_in[29];
  const float* pln_o_b   = (const float*)d_in[30];
  const float* pln_f1_w  = (const float*)d_in[31];
  const float* pln_f1_b  = (const float*)d_in[32];
  const float* pln_f2_w  = (const float*)d_in[33];
  const float* pln_f2_b  = (const float*)d_in[34];
  const float* prev_qkv  = (const float*)d_in[35];
  const float* prev_o    = (const float*)d_in[36];
  const float* prev_f1   = (const float*)d_in[37];
  const float* prev_f2   = (const float*)d_in[38];

  const long D = 1024, TD = 3072, FD = 4096, R = 4096;

  char* W = (char*)d_ws;
  size_t off = 0;
  auto alloc = [&](size_t bytes) {
    void* p = W + off;
    off = (off + bytes + 255) & ~(size_t)255;
    return p;
  };
  char* GOUT = (char*)alloc(67108864);   // fused GEMM out / staging / scores+P / partials
  u16*  RC   = (u16*)alloc(33554432);    // proto T / m_qkv / h
  u16*  wq   = (u16*)alloc(2 * TD * D * 2);   // [mu; eff] stacked along N
  u16*  wo   = (u16*)alloc(2 * D * D * 2);
  u16*  wf1  = (u16*)alloc(2 * FD * D * 2);
  u16*  wf2  = (u16*)alloc(2 * D * FD * 2);
  float* X1  = (float*)alloc(R * D * 4);
  u16*  P1   = (u16*)alloc(R * D * 2);        // attn_in / ffn_in bf16
  u16*  VT   = (u16*)alloc(2 * D * 2048 * 2);
  u16*  AOB  = (u16*)alloc(R * D * 2);
  float* pnq     = (float*)alloc(TD * 4);
  float* pno     = (float*)alloc(D * 4);
  float* pnf1    = (float*)alloc(FD * 4);
  float* pnf2    = (float*)alloc(D * 4);
  float* rn_ain  = (float*)alloc(R * 4);
  float* rn_aout = (float*)alloc(R * 4);
  float* rn_ffn  = (float*)alloc(R * 4);
  float* rn_h    = (float*)alloc(R * 4);
  size_t need = off;

  if (n_in < 39 || need > ws_size) {
    long n = out_size;
    fillv<<<dim3((unsigned)((n + 255) / 256)), 256, 0, stream>>>((float*)d_out, n, 12345.0f);
    return;
  }

  // overlays inside GOUT
  u16* SA = (u16*)GOUT;                       // staging A (prev), up to 24 MiB
  u16* SB = (u16*)(GOUT + 25165824);          // staging B (pt), up to ~34 MiB
  float* SCORES = (float*)GOUT;               // [2][2048][2048] fp32 = 32 MiB
  u16* PB = (u16*)(GOUT + 33554432);          // [2][2048][2048] bf16 = 16 MiB

  auto cvt = [&](const float* s, u16* d, long n) {
    long n4 = n >> 2;
    cvt_bf16<<<dim3((unsigned)((n4 + 255) / 256)), 256, 0, stream>>>(s, d, n4);
  };

  // ---- phase 1: effective protos ----
  // batched qkv/o/f1 protos (all N=1024, K=1024): z=0 f1(M=4096), z=1 qkv(3072), z=2 o(1024)
  cvt(prev_f1,  SA,            FD * D);
  cvt(prev_qkv, SA + 4194304,  TD * D);
  cvt(prev_o,   SA + 8388608,  D * D);
  cvt(pt_f1,    SB,            D * D);
  cvt(pt_qkv,   SB + 1048576,  D * D);
  cvt(pt_o,     SB + 2097152,  D * D);
  {
    long Mz = 4096L | (3072L << 16) | (1024L << 32);
    gemm_bt<u16><<<dim3(32, 8, 3), 256, 0, stream>>>(
        SA, SB, RC, 4096, 1024, 1024, 1024, 1024, 5, 4194304, Mz, 4194304);
  }
  ln_add_norm<<<4096, 256, 0, stream>>>(RC, nullptr, f1_proto, pln_f1_w, pln_f1_b,
                                        wf1 + (size_t)FD * D, pnf1, 1024);
  ln_add_norm<<<3072, 256, 0, stream>>>(RC + 4194304, nullptr, qkv_proto, pln_qkv_w,
                                        pln_qkv_b, wq + (size_t)TD * D, pnq, 1024);
  ln_add_norm<<<1024, 256, 0, stream>>>(RC + 8388608, nullptr, o_proto, pln_o_w,
                                        pln_o_b, wo + (size_t)D * D, pno, 1024);
  // f2 proto: M=1024, N=4096, K=4096; split-K x2, bf16 partials in RC
  cvt(prev_f2, SA, D * FD);
  cvt(pt_f2,   SB, (long)FD * FD);
  gemm_bt<u16><<<dim3(8, 32, 2), 256, 0, stream>>>(
      SA, SB, RC, 1024, 4096, 4096, 4096, 4096, 1, 0, 0, 0);
  ln_add_norm<<<1024, 256, 0, stream>>>(RC, RC + 4194304, f2_proto, pln_f2_w, pln_f2_b,
                                        wf2 + (size_t)D * FD, pnf2, 4096);
  cvt(qkv_mu, wq, TD * D);
  cvt(o_mu,   wo, D * D);
  cvt(f1_mu,  wf1, FD * D);
  cvt(f2_mu,  wf2, D * FD);

  // ---- phase 2: attention input LN + fused qkv SPL + RoPE ----
  ln_rows<<<4096, 256, 0, stream>>>(x, ln1_w, ln1_b, P1, rn_ain, 1024);
  gemm_bt<u16><<<dim3(32, 48, 1), 256, 0, stream>>>(
      P1, wq, (u16*)GOUT, 4096, 6144, 1024, 1024, 1024, 0, 0, 0, 0);
  spl_rope_row<<<4096, 256, 0, stream>>>(
      (u16*)GOUT, qkv_bias, qkv_gate, rn_ain, pnq, cosT, sinT, RC);

  // ---- phase 3: attention (batched) ----
  vtrans<<<dim3(64, 32, 2), dim3(32, 8), 0, stream>>>(RC, VT);
  gemm_bt<float><<<dim3(136, 1, 2), 256, 0, stream>>>(
      RC, RC + 1024, SCORES, 2048, 2048, 1024, 3072, 3072,
      3, 2048L * 3072, 2048L * 3072, 1L << 22);
  softmax_causal<<<4096, 256, 0, stream>>>(SCORES, PB);
  gemm_bt<u16><<<dim3(16, 8, 2), 256, 0, stream>>>(
      PB, VT, AOB, 2048, 1024, 2048, 2048, 2048,
      4, 1L << 22, 1024L * 2048, 2048L * 1024);
  rownorm_bf<<<4096, 256, 0, stream>>>(AOB, rn_aout, 1024);

  // ---- phase 4: fused o SPL + residual + LN2 ----
  gemm_bt<u16><<<dim3(32, 16, 1), 256, 0, stream>>>(
      AOB, wo, (u16*)GOUT, 4096, 2048, 1024, 1024, 1024, 0, 0, 0, 0);
  spl_o_ln_row<<<4096, 256, 0, stream>>>(
      (u16*)GOUT, o_bias, o_gate, rn_aout, pno, x, ln2_w, ln2_b, X1, P1, rn_ffn);

  // ---- phase 5: FFN ----
  gemm_bt<u16><<<dim3(32, 64, 1), 256, 0, stream>>>(
      P1, wf1, (u16*)GOUT, 4096, 8192, 1024, 1024, 1024, 0, 0, 0, 0);
  spl_f1_row<<<4096, 256, 0, stream>>>(
      (u16*)GOUT, f1_bias, f1_gate, rn_ffn, pnf1, RC, rn_h);      // h -> RC
  // f2 fused, split-K x2, bf16 partials [2][4096][2048] = 32 MiB in GOUT
  gemm_bt<u16><<<dim3(32, 16, 2), 256, 0, stream>>>(
      RC, wf2, (u16*)GOUT, 4096, 2048, 4096, 4096, 4096, 1, 0, 0, 0);
  spl_epi_p<<<4096, 256, 0, stream>>>(
      (u16*)GOUT, (u16*)GOUT + 8388608, f2_bias, f2_gate, rn_h, pnf2,
      X1, (float*)d_out);
}

// Round 5
// 589.671 us; speedup vs baseline: 1.4799x; 1.0107x over previous
//
#include <hip/hip_runtime.h>
#include <cstdint>

typedef unsigned short u16;
typedef __attribute__((ext_vector_type(8))) short sh8;   // 8 bf16 (4 VGPRs)
typedef __attribute__((ext_vector_type(4))) float f32x4;

struct __align__(8) us4 { u16 x, y, z, w; };

__device__ __forceinline__ u16 f2bf(float f) {
  unsigned u = __float_as_uint(f);
  u += 0x7FFFu + ((u >> 16) & 1u);   // RNE
  return (u16)(u >> 16);
}
__device__ __forceinline__ float bf2f(u16 h) {
  return __uint_as_float((unsigned)h << 16);
}

// ---------------- block reductions (blockDim.x == 256) ----------------
__device__ __forceinline__ float blk_sum(float v, float* red) {
#pragma unroll
  for (int o = 32; o; o >>= 1) v += __shfl_xor(v, o);
  __syncthreads();
  if ((threadIdx.x & 63) == 0) red[threadIdx.x >> 6] = v;
  __syncthreads();
  return red[0] + red[1] + red[2] + red[3];
}
__device__ __forceinline__ float blk_max(float v, float* red) {
#pragma unroll
  for (int o = 32; o; o >>= 1) v = fmaxf(v, __shfl_xor(v, o));
  __syncthreads();
  if ((threadIdx.x & 63) == 0) red[threadIdx.x >> 6] = v;
  __syncthreads();
  return fmaxf(fmaxf(red[0], red[1]), fmaxf(red[2], red[3]));
}

// ---------------- fp32 -> bf16 ----------------
__global__ void cvt_bf16(const float* __restrict__ S, u16* __restrict__ D, long n4) {
  long i = (long)blockIdx.x * blockDim.x + threadIdx.x;
  if (i >= n4) return;
  float4 v = ((const float4*)S)[i];
  us4 o; o.x = f2bf(v.x); o.y = f2bf(v.y); o.z = f2bf(v.z); o.w = f2bf(v.w);
  ((us4*)D)[i] = o;
}

__global__ void fillv(float* __restrict__ o, long n, float v) {
  long i = (long)blockIdx.x * blockDim.x + threadIdx.x;
  if (i < n) o[i] = v;
}

#define GL16(gp, lp)                                                        \
  __builtin_amdgcn_global_load_lds(                                         \
      (const __attribute__((address_space(1))) void*)(gp),                  \
      (__attribute__((address_space(3))) void*)(lp), 16, 0, 0)

// ================= 256x256 pipelined GEMM: C = A[M,K] @ B[N,K]^T =================
// 512 threads (8 waves, 2M x 4N), BK=32, 4-slot LDS ring (128 KiB), counted vmcnt,
// XOR bank-swizzle (byte ^= ((byte>>7)&3)<<4) with inverse-swizzled global source.
// kchunk > 0: split-K over blockIdx.z (C += z*M*N, K range [z*kchunk, +kchunk)).
template <typename CT>
__global__ __launch_bounds__(512, 1) void gemm256(
    const u16* __restrict__ A, const u16* __restrict__ B, CT* __restrict__ C,
    int M, int N, int K, int lda, int ldb, int kchunk) {
  extern __shared__ u16 lds[];   // 4 slots x (A 8192 + B 8192) u16 = 128 KiB
  int tid = threadIdx.x;
  int wid = tid >> 6, lane = tid & 63;
  int wm = wid >> 2, wn = wid & 3;
  int bm = blockIdx.x, bn = blockIdx.y;
  int k0s = 0, nt;
  if (kchunk) {
    k0s = blockIdx.z * kchunk;
    C += (size_t)blockIdx.z * M * (size_t)N;
    nt = kchunk >> 5;
  } else {
    nt = K >> 5;
  }
  const size_t baseArow = (size_t)bm * 256;
  const size_t baseBrow = (size_t)bn * 256;

  // ---- staging geometry: thread handles chunk ci (and ci+512) of each tile ----
  int ci = (wid << 6) + lane;                 // 0..511
  int rowS = ci >> 2;                          // 0..127 (round1: +128)
  int kcS = (ci ^ (ci >> 3)) & 3;              // inverse-swizzled k-chunk
  const u16* gA0 = A + (baseArow + rowS) * lda + k0s + kcS * 8;
  const u16* gA1 = gA0 + (size_t)128 * lda;
  const u16* gB0 = B + (baseBrow + rowS) * ldb + k0s + kcS * 8;
  const u16* gB1 = gB0 + (size_t)128 * ldb;
  u16* dBase = lds + (wid << 9);               // wave-uniform lane-linear dest

  // ---- swizzled read offsets (u16 units within slot) ----
  int l15 = lane & 15, l4 = lane >> 4;
  int aoff[8], boff[4];
#pragma unroll
  for (int fr = 0; fr < 8; ++fr) {
    int by = (wm * 128 + fr * 16 + l15) * 64 + l4 * 16;
    aoff[fr] = (by ^ (((by >> 7) & 3) << 4)) >> 1;
  }
#pragma unroll
  for (int fc = 0; fc < 4; ++fc) {
    int by = (wn * 64 + fc * 16 + l15) * 64 + l4 * 16;
    boff[fc] = 8192 + ((by ^ (((by >> 7) & 3) << 4)) >> 1);
  }

  f32x4 acc[8][4];
  const f32x4 zf = {0.f, 0.f, 0.f, 0.f};
#pragma unroll
  for (int i = 0; i < 8; ++i)
#pragma unroll
    for (int j = 0; j < 4; ++j) acc[i][j] = zf;

#define STAGE256(ts)                                                  \
  do {                                                                \
    int ss_ = (ts) & 3;                                               \
    int kk_ = (ts) << 5;                                              \
    u16* d_ = dBase + ss_ * 16384;                                    \
    GL16(gA0 + kk_, d_);                                              \
    GL16(gA1 + kk_, d_ + 4096);                                       \
    GL16(gB0 + kk_, d_ + 8192);                                       \
    GL16(gB1 + kk_, d_ + 12288);                                      \
  } while (0)

  // prologue: 3 tiles in flight, tile 0 landed
  STAGE256(0);
  STAGE256(1);
  STAGE256(2);
  asm volatile("s_waitcnt vmcnt(8)" ::: "memory");
  __builtin_amdgcn_s_barrier();
  __builtin_amdgcn_sched_barrier(0);

  for (int t = 0; t < nt; ++t) {
    int ts = t + 3;
    if (ts < nt) STAGE256(ts);

    const u16* sl = lds + (t & 3) * 16384;
    sh8 af[8], bfv[4];
#pragma unroll
    for (int fc = 0; fc < 4; ++fc) bfv[fc] = *(const sh8*)(sl + boff[fc]);
#pragma unroll
    for (int fr = 0; fr < 8; ++fr) af[fr] = *(const sh8*)(sl + aoff[fr]);

    __builtin_amdgcn_s_setprio(1);
#pragma unroll
    for (int fr = 0; fr < 8; ++fr)
#pragma unroll
      for (int fc = 0; fc < 4; ++fc)
        acc[fr][fc] = __builtin_amdgcn_mfma_f32_16x16x32_bf16(af[fr], bfv[fc],
                                                              acc[fr][fc], 0, 0, 0);
    __builtin_amdgcn_s_setprio(0);

    int rem = nt - 2 - t;
    if (rem >= 2)      asm volatile("s_waitcnt vmcnt(8)" ::: "memory");
    else if (rem == 1) asm volatile("s_waitcnt vmcnt(4)" ::: "memory");
    else if (rem == 0) asm volatile("s_waitcnt vmcnt(0)" ::: "memory");
    if (t < nt - 1) {
      __builtin_amdgcn_s_barrier();
      __builtin_amdgcn_sched_barrier(0);
    }
  }
#undef STAGE256

  // C/D layout (m89): col = lane&15, row = (lane>>4)*4 + reg
  int cr = l4 << 2, cc = l15;
  const size_t rbase = baseArow + wm * 128 + cr;
  const size_t cbase = baseBrow + wn * 64 + cc;
#pragma unroll
  for (int fr = 0; fr < 8; ++fr)
#pragma unroll
    for (int fc = 0; fc < 4; ++fc) {
      size_t cb = (rbase + fr * 16) * (size_t)N + cbase + fc * 16;
#pragma unroll
      for (int r = 0; r < 4; ++r) {
        float v = acc[fr][fc][r];
        if constexpr (sizeof(CT) == 2) C[cb + (size_t)r * N] = (CT)f2bf(v);
        else                           C[cb + (size_t)r * N] = v;
      }
    }
}

// ---------------- bf16 GEMM: C[M,N] = A[M,K] @ B[N,K]^T (128^2, m97) ----------------
// mode 0: plain 2D grid
// mode 1: split-K over blockIdx.z; C gets per-chunk partials at stride M*N
// mode 2: batched over z (strides zsA/zsB/zsC)
// mode 3: batched + causal lower-triangle tile enumeration on blockIdx.x
// mode 4: batched + causal K-cap (k0e = (bm+1)*128)  [PV]
// mode 5: multi-M batched: Mz packed 16b/z in zsB, B z-stride 2^20, A/C via zsA/zsC
template <typename CT>
__global__ __launch_bounds__(256, 2) void gemm_bt(
    const u16* __restrict__ A, const u16* __restrict__ B, CT* __restrict__ C,
    int M, int N, int K, int lda, int ldb,
    int mode, long zsA, long zsB, long zsC) {
  int bm, bn;
  int z = blockIdx.z;
  if (mode == 3) {
    int t = blockIdx.x;
    int m = (int)floorf((sqrtf(8.f * t + 1.f) - 1.f) * 0.5f);
    while ((m + 1) * (m + 2) / 2 <= t) ++m;
    while (m * (m + 1) / 2 > t) --m;
    bm = m; bn = t - m * (m + 1) / 2;
  } else {
    bm = blockIdx.x; bn = blockIdx.y;
  }
  int k0s = 0, k0e = K;
  if (mode == 1) {
    int kc = K / gridDim.z;
    k0s = z * kc; k0e = k0s + kc;
    C += (size_t)z * M * (size_t)N;
  } else if (mode == 2 || mode == 3) {
    A += (size_t)z * zsA; B += (size_t)z * zsB; C += (size_t)z * zsC;
  } else if (mode == 4) {
    A += (size_t)z * zsA; B += (size_t)z * zsB; C += (size_t)z * zsC;
    k0e = (bm + 1) * 128;
  } else if (mode == 5) {
    int Mz = (int)((zsB >> (z * 16)) & 0xFFFF);
    if (bm * 128 >= Mz) return;
    A += (size_t)z * zsA; B += (size_t)z * 1048576; C += (size_t)z * zsC;
  }

  __shared__ __align__(16) u16 As[128 * 32];
  __shared__ __align__(16) u16 Bs[128 * 32];
  int tid = threadIdx.x, wid = tid >> 6, lane = tid & 63;
  int wr = (wid >> 1) << 6, wc = (wid & 1) << 6;
  int lr = lane & 15, lk = (lane >> 4) << 3;

  f32x4 acc[4][4];
  const f32x4 zf = {0.f, 0.f, 0.f, 0.f};
#pragma unroll
  for (int i = 0; i < 4; ++i)
#pragma unroll
    for (int j = 0; j < 4; ++j) acc[i][j] = zf;

  int r0 = tid >> 2, c0 = (tid & 3) << 3;
  const size_t baseA = (size_t)bm * 128, baseB = (size_t)bn * 128;
  const u16* Ab = A + baseA * lda;
  const u16* Bp = B + baseB * ldb;

  for (int k0 = k0s; k0 < k0e; k0 += 32) {
    GL16(Ab + (size_t)r0 * lda + k0 + c0, As + (wid << 9));
    GL16(Ab + (size_t)(64 + r0) * lda + k0 + c0, As + 2048 + (wid << 9));
    GL16(Bp + (size_t)r0 * ldb + k0 + c0, Bs + (wid << 9));
    GL16(Bp + (size_t)(64 + r0) * ldb + k0 + c0, Bs + 2048 + (wid << 9));
    __syncthreads();
    sh8 af[4], bfr[4];
#pragma unroll
    for (int f = 0; f < 4; ++f) {
      af[f]  = *(const sh8*)(As + (wr + f * 16 + lr) * 32 + lk);
      bfr[f] = *(const sh8*)(Bs + (wc + f * 16 + lr) * 32 + lk);
    }
#pragma unroll
    for (int i = 0; i < 4; ++i)
#pragma unroll
      for (int j = 0; j < 4; ++j)
        acc[i][j] = __builtin_amdgcn_mfma_f32_16x16x32_bf16(af[i], bfr[j], acc[i][j], 0, 0, 0);
    __syncthreads();
  }

  int cr = (lane >> 4) << 2, cc = lane & 15;
#pragma unroll
  for (int i = 0; i < 4; ++i)
#pragma unroll
    for (int j = 0; j < 4; ++j) {
      size_t cb = (baseA + wr + i * 16 + cr) * (size_t)N + (baseB + wc + j * 16 + cc);
#pragma unroll
      for (int r = 0; r < 4; ++r) {
        float v = acc[i][j][r];
        if constexpr (sizeof(CT) == 2) C[cb + (size_t)r * N] = (CT)f2bf(v);
        else                           C[cb + (size_t)r * N] = v;
      }
    }
}

// ---------------- row LayerNorm (fp32 in) -> bf16 out + row L2 norm ----------------
__global__ void ln_rows(const float* __restrict__ X, const float* __restrict__ w,
                        const float* __restrict__ b, u16* __restrict__ Y,
                        float* __restrict__ norms, int C) {
  __shared__ float red[4];
  int row = blockIdx.x;
  const float* x = X + (size_t)row * C;
  int nv = C >> 2;
  float s = 0.f, ss = 0.f;
  for (int i = threadIdx.x; i < nv; i += 256) {
    float4 v = ((const float4*)x)[i];
    s += v.x + v.y + v.z + v.w;
    ss += v.x * v.x + v.y * v.y + v.z * v.z + v.w * v.w;
  }
  s = blk_sum(s, red);
  ss = blk_sum(ss, red);
  float mean = s / C;
  float inv = rsqrtf(fmaxf(ss / C - mean * mean, 0.f) + 1e-5f);
  float nrm = 0.f;
  for (int i = threadIdx.x; i < nv; i += 256) {
    float4 v = ((const float4*)x)[i];
    float4 wv = ((const float4*)w)[i];
    float4 bv = ((const float4*)b)[i];
    float y0 = (v.x - mean) * inv * wv.x + bv.x;
    float y1 = (v.y - mean) * inv * wv.y + bv.y;
    float y2 = (v.z - mean) * inv * wv.z + bv.z;
    float y3 = (v.w - mean) * inv * wv.w + bv.w;
    nrm += y0 * y0 + y1 * y1 + y2 * y2 + y3 * y3;
    us4 o; o.x = f2bf(y0); o.y = f2bf(y1); o.z = f2bf(y2); o.w = f2bf(y3);
    ((us4*)(Y + (size_t)row * C))[i] = o;
  }
  nrm = blk_sum(nrm, red);
  if (threadIdx.x == 0) norms[row] = fmaxf(sqrtf(nrm), 1e-12f);
}

// ------- eff proto: E = proto + LN(T0 [+T1]) -> bf16 + row norm (T bf16) -------
__global__ void ln_add_norm(const u16* __restrict__ T0, const u16* __restrict__ T1,
                            const float* __restrict__ P,
                            const float* __restrict__ w, const float* __restrict__ b,
                            u16* __restrict__ E, float* __restrict__ norms, int C) {
  __shared__ float red[4];
  int row = blockIdx.x;
  const us4* t0 = (const us4*)(T0 + (size_t)row * C);
  const us4* t1 = T1 ? (const us4*)(T1 + (size_t)row * C) : nullptr;
  const float* p = P + (size_t)row * C;
  int nv = C >> 2;
  float s = 0.f, ss = 0.f;
  for (int i = threadIdx.x; i < nv; i += 256) {
    us4 v = t0[i];
    float f0 = bf2f(v.x), f1 = bf2f(v.y), f2 = bf2f(v.z), f3 = bf2f(v.w);
    if (t1) {
      us4 v1 = t1[i];
      f0 += bf2f(v1.x); f1 += bf2f(v1.y); f2 += bf2f(v1.z); f3 += bf2f(v1.w);
    }
    s += f0 + f1 + f2 + f3;
    ss += f0 * f0 + f1 * f1 + f2 * f2 + f3 * f3;
  }
  s = blk_sum(s, red);
  ss = blk_sum(ss, red);
  float mean = s / C;
  float inv = rsqrtf(fmaxf(ss / C - mean * mean, 0.f) + 1e-5f);
  float nrm = 0.f;
  for (int i = threadIdx.x; i < nv; i += 256) {
    us4 v = t0[i];
    float f0 = bf2f(v.x), f1 = bf2f(v.y), f2 = bf2f(v.z), f3 = bf2f(v.w);
    if (t1) {
      us4 v1 = t1[i];
      f0 += bf2f(v1.x); f1 += bf2f(v1.y); f2 += bf2f(v1.z); f3 += bf2f(v1.w);
    }
    float4 pv = ((const float4*)p)[i];
    float4 wv = ((const float4*)w)[i];
    float4 bv = ((const float4*)b)[i];
    float y0 = pv.x + (f0 - mean) * inv * wv.x + bv.x;
    float y1 = pv.y + (f1 - mean) * inv * wv.y + bv.y;
    float y2 = pv.z + (f2 - mean) * inv * wv.z + bv.z;
    float y3 = pv.w + (f3 - mean) * inv * wv.w + bv.w;
    nrm += y0 * y0 + y1 * y1 + y2 * y2 + y3 * y3;
    us4 o; o.x = f2bf(y0); o.y = f2bf(y1); o.z = f2bf(y2); o.w = f2bf(y3);
    ((us4*)(E + (size_t)row * C))[i] = o;
  }
  nrm = blk_sum(nrm, red);
  if (threadIdx.x == 0) norms[row] = fmaxf(sqrtf(nrm), 1e-12f);
}

// ---------------- row L2 norm of a bf16 matrix ----------------
__global__ void rownorm_bf(const u16* __restrict__ X, float* __restrict__ norms, int C) {
  __shared__ float red[4];
  int row = blockIdx.x;
  const us4* x = (const us4*)(X + (size_t)row * C);
  int nv = C >> 2;
  float nrm = 0.f;
  for (int i = threadIdx.x; i < nv; i += 256) {
    us4 v = x[i];
    float a = bf2f(v.x), b = bf2f(v.y), c = bf2f(v.z), d = bf2f(v.w);
    nrm += a * a + b * b + c * c + d * d;
  }
  nrm = blk_sum(nrm, red);
  if (threadIdx.x == 0) norms[row] = fmaxf(sqrtf(nrm), 1e-12f);
}

// ---- SPL epilogue core: o[j] for us4 at column c of stacked G row (width 2C) ----
__device__ __forceinline__ void epi4(const u16* gr, int C, int c, float rr,
                                     const float* bias, const float* gate,
                                     const float* cn, float* o) {
  us4 cv = *(const us4*)(gr + c);
  us4 dv = *(const us4*)(gr + C + c);
  float4 bv = *(const float4*)(bias + c);
  float4 gv = *(const float4*)(gate + c);
  float4 nv = *(const float4*)(cn + c);
  float cf[4] = {bf2f(cv.x), bf2f(cv.y), bf2f(cv.z), bf2f(cv.w)};
  float df[4] = {bf2f(dv.x), bf2f(dv.y), bf2f(dv.z), bf2f(dv.w)};
  float bb[4] = {bv.x, bv.y, bv.z, bv.w};
  float gg[4] = {gv.x, gv.y, gv.z, gv.w};
  float nn[4] = {nv.x, nv.y, nv.z, nv.w};
#pragma unroll
  for (int j = 0; j < 4; ++j) {
    float sc = df[j] / (rr * nn[j]);
    o[j] = (cf[j] + bb[j]) * fmaxf(sc - gg[j], 0.f);
  }
}

// --------- fused qkv SPL epilogue + RoPE, one block per row ----------
__global__ void spl_rope_row(const u16* __restrict__ G, const float* __restrict__ bias,
                             const float* __restrict__ gate, const float* __restrict__ rn,
                             const float* __restrict__ cn, const float* __restrict__ CT_,
                             const float* __restrict__ ST_, u16* __restrict__ MQ) {
  int r = blockIdx.x;
  int s = r & 2047;
  const u16* gr = G + (size_t)r * 6144;
  u16* outr = MQ + (size_t)r * 3072;
  float rr = rn[r];
  int t = threadIdx.x;

  int qk = (t >> 7);              // 0 = q, 1 = k
  int c = qk * 1024 + ((t & 127) << 2);
  int d = c - qk * 1024;
  float a0[4], a1[4];
  epi4(gr, 3072, c, rr, bias, gate, cn, a0);
  epi4(gr, 3072, c + 512, rr, bias, gate, cn, a1);
  const float* ct = CT_ + (size_t)s * 1024;
  const float* st = ST_ + (size_t)s * 1024;
  float4 c0 = *(const float4*)(ct + d);
  float4 s0 = *(const float4*)(st + d);
  float4 c1 = *(const float4*)(ct + d + 512);
  float4 s1 = *(const float4*)(st + d + 512);
  float cc0[4] = {c0.x, c0.y, c0.z, c0.w}, ss0[4] = {s0.x, s0.y, s0.z, s0.w};
  float cc1[4] = {c1.x, c1.y, c1.z, c1.w}, ss1[4] = {s1.x, s1.y, s1.z, s1.w};
  us4 o0, o1;
  o0.x = f2bf(a0[0] * cc0[0] - a1[0] * ss0[0]);
  o0.y = f2bf(a0[1] * cc0[1] - a1[1] * ss0[1]);
  o0.z = f2bf(a0[2] * cc0[2] - a1[2] * ss0[2]);
  o0.w = f2bf(a0[3] * cc0[3] - a1[3] * ss0[3]);
  o1.x = f2bf(a1[0] * cc1[0] + a0[0] * ss1[0]);
  o1.y = f2bf(a1[1] * cc1[1] + a0[1] * ss1[1]);
  o1.z = f2bf(a1[2] * cc1[2] + a0[2] * ss1[2]);
  o1.w = f2bf(a1[3] * cc1[3] + a0[3] * ss1[3]);
  *(us4*)(outr + c) = o0;
  *(us4*)(outr + c + 512) = o1;

  int cv_ = 2048 + (t << 2);
  float vv[4];
  epi4(gr, 3072, cv_, rr, bias, gate, cn, vv);
  us4 ov; ov.x = f2bf(vv[0]); ov.y = f2bf(vv[1]); ov.z = f2bf(vv[2]); ov.w = f2bf(vv[3]);
  *(us4*)(outr + cv_) = ov;
}

// --------- fused f1 SPL epilogue (relu) + row norm of h, one block per row ---------
__global__ void spl_f1_row(const u16* __restrict__ G, const float* __restrict__ bias,
                           const float* __restrict__ gate, const float* __restrict__ rn,
                           const float* __restrict__ cn, u16* __restrict__ H,
                           float* __restrict__ rn_h) {
  __shared__ float red[4];
  int r = blockIdx.x;
  const u16* gr = G + (size_t)r * 8192;
  u16* hr = H + (size_t)r * 4096;
  float rr = rn[r];
  float nrm = 0.f;
  for (int c = threadIdx.x << 2; c < 4096; c += 1024) {
    float o[4];
    epi4(gr, 4096, c, rr, bias, gate, cn, o);
#pragma unroll
    for (int j = 0; j < 4; ++j) {
      o[j] = fmaxf(o[j], 0.f);
      nrm += o[j] * o[j];
    }
    us4 ov; ov.x = f2bf(o[0]); ov.y = f2bf(o[1]); ov.z = f2bf(o[2]); ov.w = f2bf(o[3]);
    *(us4*)(hr + c) = ov;
  }
  nrm = blk_sum(nrm, red);
  if (threadIdx.x == 0) rn_h[r] = fmaxf(sqrtf(nrm), 1e-12f);
}

// --- fused o SPL + residual -> X1 (fp32), then LN2 -> bf16 + rn_ffn, one block/row ---
__global__ void spl_o_ln_row(const u16* __restrict__ G, const float* __restrict__ bias,
                             const float* __restrict__ gate, const float* __restrict__ rn,
                             const float* __restrict__ cn, const float* __restrict__ xres,
                             const float* __restrict__ lw, const float* __restrict__ lb,
                             float* __restrict__ X1, u16* __restrict__ Y,
                             float* __restrict__ rn_ffn) {
  __shared__ float red[4];
  int r = blockIdx.x;
  int c = threadIdx.x << 2;
  const u16* gr = G + (size_t)r * 2048;
  float o[4];
  epi4(gr, 1024, c, rn[r], bias, gate, cn, o);
  float4 rv = *(const float4*)(xres + (size_t)r * 1024 + c);
  o[0] += rv.x; o[1] += rv.y; o[2] += rv.z; o[3] += rv.w;
  float4 xo = {o[0], o[1], o[2], o[3]};
  *(float4*)(X1 + (size_t)r * 1024 + c) = xo;
  float s = o[0] + o[1] + o[2] + o[3];
  float ss = o[0] * o[0] + o[1] * o[1] + o[2] * o[2] + o[3] * o[3];
  s = blk_sum(s, red);
  ss = blk_sum(ss, red);
  float mean = s * (1.f / 1024.f);
  float inv = rsqrtf(fmaxf(ss * (1.f / 1024.f) - mean * mean, 0.f) + 1e-5f);
  float4 wv = *(const float4*)(lw + c);
  float4 bv = *(const float4*)(lb + c);
  float ww[4] = {wv.x, wv.y, wv.z, wv.w}, bb[4] = {bv.x, bv.y, bv.z, bv.w};
  float nrm = 0.f;
  us4 ov;
  u16* op = (u16*)&ov;
#pragma unroll
  for (int j = 0; j < 4; ++j) {
    float y = (o[j] - mean) * inv * ww[j] + bb[j];
    nrm += y * y;
    op[j] = f2bf(y);
  }
  *(us4*)(Y + (size_t)r * 1024 + c) = ov;
  nrm = blk_sum(nrm, red);
  if (threadIdx.x == 0) rn_ffn[r] = fmaxf(sqrtf(nrm), 1e-12f);
}

// ------ final SPL epilogue: bf16 split-K partial pair + residual -> fp32 out ------
__global__ void spl_epi_p(const u16* __restrict__ G0, const u16* __restrict__ G1,
                          const float* __restrict__ bias, const float* __restrict__ gate,
                          const float* __restrict__ rn, const float* __restrict__ cn,
                          const float* __restrict__ resid, float* __restrict__ out) {
  int r = blockIdx.x;
  int c = threadIdx.x << 2;
  size_t rowb = (size_t)r * 2048;
  us4 c0 = *(const us4*)(G0 + rowb + c);
  us4 c1 = *(const us4*)(G1 + rowb + c);
  us4 d0 = *(const us4*)(G0 + rowb + 1024 + c);
  us4 d1 = *(const us4*)(G1 + rowb + 1024 + c);
  float4 bv = *(const float4*)(bias + c);
  float4 gv = *(const float4*)(gate + c);
  float4 nv = *(const float4*)(cn + c);
  float4 rv = *(const float4*)(resid + (size_t)r * 1024 + c);
  float rr = rn[r];
  float cf[4] = {bf2f(c0.x) + bf2f(c1.x), bf2f(c0.y) + bf2f(c1.y),
                 bf2f(c0.z) + bf2f(c1.z), bf2f(c0.w) + bf2f(c1.w)};
  float df[4] = {bf2f(d0.x) + bf2f(d1.x), bf2f(d0.y) + bf2f(d1.y),
                 bf2f(d0.z) + bf2f(d1.z), bf2f(d0.w) + bf2f(d1.w)};
  float bb[4] = {bv.x, bv.y, bv.z, bv.w};
  float gg[4] = {gv.x, gv.y, gv.z, gv.w};
  float nn[4] = {nv.x, nv.y, nv.z, nv.w};
  float re[4] = {rv.x, rv.y, rv.z, rv.w};
  float4 ov;
  float* op = (float*)&ov;
#pragma unroll
  for (int j = 0; j < 4; ++j) {
    float sc = df[j] / (rr * nn[j]);
    op[j] = (cf[j] + bb[j]) * fmaxf(sc - gg[j], 0.f) + re[j];
  }
  *(float4*)(out + (size_t)r * 1024 + c) = ov;
}

// ---------------- V transpose (bf16 m_qkv -> VT[b][d][s]) ----------------
__global__ void vtrans(const u16* __restrict__ MQ, u16* __restrict__ VT) {
  __shared__ u16 tile[32][33];
  int b = blockIdx.z;
  int s0 = blockIdx.x << 5, d0 = blockIdx.y << 5;
  int tx = threadIdx.x, ty = threadIdx.y;
  for (int r = ty; r < 32; r += 8)
    tile[r][tx] = MQ[((size_t)(b * 2048 + s0 + r)) * 3072 + 2048 + d0 + tx];
  __syncthreads();
  for (int r = ty; r < 32; r += 8)
    VT[(size_t)b * 1024 * 2048 + (size_t)(d0 + r) * 2048 + s0 + tx] = tile[tx][r];
}

// ---- causal softmax over [2][2048][2048] scores, scale 1/32 -> bf16 P ----
__global__ void softmax_causal(const float* __restrict__ S, u16* __restrict__ P) {
  __shared__ float red[4];
  int b = blockIdx.x >> 11;
  int q = blockIdx.x & 2047;
  const float* row = S + ((size_t)b << 22) + (size_t)q * 2048;
  u16* prow = P + ((size_t)b << 22) + (size_t)q * 2048;
  int nv = q + 1;
  int wcap = ((q >> 7) + 1) << 7;
  int base = threadIdx.x * 8;
  float e[8];
  float m = -3.4e38f;
  float xv[8];
  bool live = base < nv;
  if (live) {
    float4 a = *(const float4*)(row + base);
    float4 bq = *(const float4*)(row + base + 4);
    xv[0] = a.x; xv[1] = a.y; xv[2] = a.z; xv[3] = a.w;
    xv[4] = bq.x; xv[5] = bq.y; xv[6] = bq.z; xv[7] = bq.w;
#pragma unroll
    for (int j = 0; j < 8; ++j) {
      xv[j] *= 0.03125f;
      if (base + j < nv) m = fmaxf(m, xv[j]);
    }
  }
  m = blk_max(m, red);
  float ssum = 0.f;
#pragma unroll
  for (int j = 0; j < 8; ++j) {
    e[j] = (live && base + j < nv) ? __expf(xv[j] - m) : 0.f;
    ssum += e[j];
  }
  ssum = blk_sum(ssum, red);
  float invs = 1.f / ssum;
  if (base < wcap) {
    us4 o;
    o.x = f2bf(e[0] * invs); o.y = f2bf(e[1] * invs);
    o.z = f2bf(e[2] * invs); o.w = f2bf(e[3] * invs);
    ((us4*)prow)[threadIdx.x * 2] = o;
    o.x = f2bf(e[4] * invs); o.y = f2bf(e[5] * invs);
    o.z = f2bf(e[6] * invs); o.w = f2bf(e[7] * invs);
    ((us4*)prow)[threadIdx.x * 2 + 1] = o;
  }
}

// =============================== launcher ===============================
extern "C" void kernel_launch(void* const* d_in, const int* in_sizes, int n_in,
                              void* d_out, int out_size, void* d_ws, size_t ws_size,
                              hipStream_t stream) {
  (void)in_sizes;
  const float* x         = (const float*)d_in[0];
  const float* cosT      = (const float*)d_in[1];
  const float* sinT      = (const float*)d_in[2];
  const float* ln1_w     = (const float*)d_in[3];
  const float* ln1_b     = (const float*)d_in[4];
  const float* ln2_w     = (const float*)d_in[5];
  const float* ln2_b     = (const float*)d_in[6];
  const float* qkv_mu    = (const float*)d_in[7];
  const float* qkv_proto = (const float*)d_in[8];
  const float* qkv_bias  = (const float*)d_in[9];
  const float* qkv_gate  = (const float*)d_in[10];
  const float* o_mu      = (const float*)d_in[11];
  const float* o_proto   = (const float*)d_in[12];
  const float* o_bias    = (const float*)d_in[13];
  const float* o_gate    = (const float*)d_in[14];
  const float* f1_mu     = (const float*)d_in[15];
  const float* f1_proto  = (const float*)d_in[16];
  const float* f1_bias   = (const float*)d_in[17];
  const float* f1_gate   = (const float*)d_in[18];
  const float* f2_mu     = (const float*)d_in[19];
  const float* f2_proto  = (const float*)d_in[20];
  const float* f2_bias   = (const float*)d_in[21];
  const float* f2_gate   = (const float*)d_in[22];
  const float* pt_qkv    = (const float*)d_in[23];
  const float* pt_o      = (const float*)d_in[24];
  const float* pt_f1     = (const float*)d_in[25];
  const float* pt_f2     = (const float*)d_in[26];
  const float* pln_qkv_w = (const float*)d_in[27];
  const float* pln_qkv_b = (const float*)d_in[28];
  const float* pln_o_w   = (const float*)d_in[29];
  const float* pln_o_b   = (const float*)d_in[30];
  const float* pln_f1_w  = (const float*)d_in[31];
  const float* pln_f1_b  = (const float*)d_in[32];
  const float* pln_f2_w  = (const float*)d_in[33];
  const float* pln_f2_b  = (const float*)d_in[34];
  const float* prev_qkv  = (const float*)d_in[35];
  const float* prev_o    = (const float*)d_in[36];
  const float* prev_f1   = (const float*)d_in[37];
  const float* prev_f2   = (const float*)d_in[38];

  const long D = 1024, TD = 3072, FD = 4096, R = 4096;

  char* W = (char*)d_ws;
  size_t off = 0;
  auto alloc = [&](size_t bytes) {
    void* p = W + off;
    off = (off + bytes + 255) & ~(size_t)255;
    return p;
  };
  char* GOUT = (char*)alloc(67108864);   // fused GEMM out / staging / scores+P / partials
  u16*  RC   = (u16*)alloc(33554432);    // proto T / m_qkv / h
  u16*  wq   = (u16*)alloc(2 * TD * D * 2);   // [mu; eff] stacked along N
  u16*  wo   = (u16*)alloc(2 * D * D * 2);
  u16*  wf1  = (u16*)alloc(2 * FD * D * 2);
  u16*  wf2  = (u16*)alloc(2 * D * FD * 2);
  float* X1  = (float*)alloc(R * D * 4);
  u16*  P1   = (u16*)alloc(R * D * 2);        // attn_in / ffn_in bf16
  u16*  VT   = (u16*)alloc(2 * D * 2048 * 2);
  u16*  AOB  = (u16*)alloc(R * D * 2);
  float* pnq     = (float*)alloc(TD * 4);
  float* pno     = (float*)alloc(D * 4);
  float* pnf1    = (float*)alloc(FD * 4);
  float* pnf2    = (float*)alloc(D * 4);
  float* rn_ain  = (float*)alloc(R * 4);
  float* rn_aout = (float*)alloc(R * 4);
  float* rn_ffn  = (float*)alloc(R * 4);
  float* rn_h    = (float*)alloc(R * 4);
  size_t need = off;

  if (n_in < 39 || need > ws_size) {
    long n = out_size;
    fillv<<<dim3((unsigned)((n + 255) / 256)), 256, 0, stream>>>((float*)d_out, n, 12345.0f);
    return;
  }

  // overlays inside GOUT
  u16* SA = (u16*)GOUT;                       // staging A (prev)
  u16* SB = (u16*)(GOUT + 25165824);          // staging B (pt)
  float* SCORES = (float*)GOUT;               // [2][2048][2048] fp32 = 32 MiB
  u16* PB = (u16*)(GOUT + 33554432);          // [2][2048][2048] bf16 = 16 MiB

  auto cvt = [&](const float* s, u16* d, long n) {
    long n4 = n >> 2;
    cvt_bf16<<<dim3((unsigned)((n4 + 255) / 256)), 256, 0, stream>>>(s, d, n4);
  };

  // ---- phase 1: effective protos ----
  cvt(prev_f1,  SA,            FD * D);
  cvt(prev_qkv, SA + 4194304,  TD * D);
  cvt(prev_o,   SA + 8388608,  D * D);
  cvt(pt_f1,    SB,            D * D);
  cvt(pt_qkv,   SB + 1048576,  D * D);
  cvt(pt_o,     SB + 2097152,  D * D);
  {
    long Mz = 4096L | (3072L << 16) | (1024L << 32);
    gemm_bt<u16><<<dim3(32, 8, 3), 256, 0, stream>>>(
        SA, SB, RC, 4096, 1024, 1024, 1024, 1024, 5, 4194304, Mz, 4194304);
  }
  ln_add_norm<<<4096, 256, 0, stream>>>(RC, nullptr, f1_proto, pln_f1_w, pln_f1_b,
                                        wf1 + (size_t)FD * D, pnf1, 1024);
  ln_add_norm<<<3072, 256, 0, stream>>>(RC + 4194304, nullptr, qkv_proto, pln_qkv_w,
                                        pln_qkv_b, wq + (size_t)TD * D, pnq, 1024);
  ln_add_norm<<<1024, 256, 0, stream>>>(RC + 8388608, nullptr, o_proto, pln_o_w,
                                        pln_o_b, wo + (size_t)D * D, pno, 1024);
  cvt(prev_f2, SA, D * FD);
  cvt(pt_f2,   SB, (long)FD * FD);
  gemm_bt<u16><<<dim3(8, 32, 2), 256, 0, stream>>>(
      SA, SB, RC, 1024, 4096, 4096, 4096, 4096, 1, 0, 0, 0);
  ln_add_norm<<<1024, 256, 0, stream>>>(RC, RC + 4194304, f2_proto, pln_f2_w, pln_f2_b,
                                        wf2 + (size_t)D * FD, pnf2, 4096);
  cvt(qkv_mu, wq, TD * D);
  cvt(o_mu,   wo, D * D);
  cvt(f1_mu,  wf1, FD * D);
  cvt(f2_mu,  wf2, D * FD);

  // ---- phase 2: attention input LN + fused qkv SPL + RoPE ----
  ln_rows<<<4096, 256, 0, stream>>>(x, ln1_w, ln1_b, P1, rn_ain, 1024);
  gemm256<u16><<<dim3(16, 24), 512, 131072, stream>>>(
      P1, wq, (u16*)GOUT, 4096, 6144, 1024, 1024, 1024, 0);
  spl_rope_row<<<4096, 256, 0, stream>>>(
      (u16*)GOUT, qkv_bias, qkv_gate, rn_ain, pnq, cosT, sinT, RC);

  // ---- phase 3: attention (batched) ----
  vtrans<<<dim3(64, 32, 2), dim3(32, 8), 0, stream>>>(RC, VT);
  gemm_bt<float><<<dim3(136, 1, 2), 256, 0, stream>>>(
      RC, RC + 1024, SCORES, 2048, 2048, 1024, 3072, 3072,
      3, 2048L * 3072, 2048L * 3072, 1L << 22);
  softmax_causal<<<4096, 256, 0, stream>>>(SCORES, PB);
  gemm_bt<u16><<<dim3(16, 8, 2), 256, 0, stream>>>(
      PB, VT, AOB, 2048, 1024, 2048, 2048, 2048,
      4, 1L << 22, 1024L * 2048, 2048L * 1024);
  rownorm_bf<<<4096, 256, 0, stream>>>(AOB, rn_aout, 1024);

  // ---- phase 4: fused o SPL + residual + LN2 ----
  gemm_bt<u16><<<dim3(32, 16, 1), 256, 0, stream>>>(
      AOB, wo, (u16*)GOUT, 4096, 2048, 1024, 1024, 1024, 0, 0, 0, 0);
  spl_o_ln_row<<<4096, 256, 0, stream>>>(
      (u16*)GOUT, o_bias, o_gate, rn_aout, pno, x, ln2_w, ln2_b, X1, P1, rn_ffn);

  // ---- phase 5: FFN ----
  gemm256<u16><<<dim3(16, 32), 512, 131072, stream>>>(
      P1, wf1, (u16*)GOUT, 4096, 8192, 1024, 1024, 1024, 0);
  spl_f1_row<<<4096, 256, 0, stream>>>(
      (u16*)GOUT, f1_bias, f1_gate, rn_ffn, pnf1, RC, rn_h);      // h -> RC
  gemm256<u16><<<dim3(16, 8, 2), 512, 131072, stream>>>(
      RC, wf2, (u16*)GOUT, 4096, 2048, 4096, 4096, 4096, 2048);
  spl_epi_p<<<4096, 256, 0, stream>>>(
      (u16*)GOUT, (u16*)GOUT + 8388608, f2_bias, f2_gate, rn_h, pnf2,
      X1, (float*)d_out);
}